// Round 14
// baseline (618.808 us; speedup 1.0000x reference)
//
#include <hip/hip_runtime.h>
#include <hip/hip_bf16.h>

#define NWIN 576
#define SP 36864
#define ATT_SCALE 0.17677669529663687f

typedef unsigned short u16;
typedef unsigned int u32;
typedef __attribute__((ext_vector_type(8))) __bf16 bf16x8;
typedef __attribute__((ext_vector_type(4))) float f32x4;

__device__ __forceinline__ float b2f(u16 u){ return __uint_as_float(((u32)u)<<16); }
__device__ __forceinline__ u16 f2b(float f){ u32 u = __float_as_uint(f); return (u16)((u + 0x7FFFu + ((u>>16)&1u)) >> 16); }
__device__ __forceinline__ float fast_rcp(float d){ float r; asm("v_rcp_f32 %0, %1" : "=v"(r) : "v"(d)); return r; }
__device__ __forceinline__ u32 cvtpk(float lo, float hi){ u32 r; asm("v_cvt_pk_bf16_f32 %0, %1, %2" : "=v"(r) : "v"(lo), "v"(hi)); return r; }
// tanh-form GELU: x*sigmoid(1.59577(x+0.044715x^3)); |err vs erf-GELU| <~1e-3
__device__ __forceinline__ float gelu_f(float v){
  float u = v*(1.5957691216f + 0.0713548163f*v*v);
  return v * fast_rcp(1.0f + __expf(-u));
}
__device__ __forceinline__ f32x4 mfma16(bf16x8 a, bf16x8 b, f32x4 c){
  return __builtin_amdgcn_mfma_f32_16x16x32_bf16(a, b, c, 0, 0, 0);
}

// ---------------- transpose BCHW fp32 -> NHWC bf16 (4 h-rows per block) ----------------
__global__ __launch_bounds__(256) void k_transpose(const float* __restrict__ x, u16* __restrict__ xn){
  __shared__ float tile[32][33];
  int blk = blockIdx.x;
  int b = blk / 1728; int rem = blk % 1728;
  int hg = rem / 36; int rem2 = rem % 36;
  int wt = rem2 / 6, ct = rem2 % 6;
  int t = threadIdx.x;
  int lw = t & 31, g = t >> 5;
  for (int r4 = 0; r4 < 4; ++r4){
    int h = hg*4 + r4;
    for (int r = 0; r < 4; ++r){
      int cl = g + r*8;
      tile[cl][lw] = x[(((size_t)b*192 + ct*32 + cl)*192 + h)*192 + wt*32 + lw];
    }
    __syncthreads();
    for (int r = 0; r < 4; ++r){
      int wl = g + r*8;
      xn[(((size_t)b*192 + h)*192 + wt*32 + wl)*192 + ct*32 + lw] = f2b(tile[lw][wl]);
    }
    __syncthreads();
  }
}

// ---------------- all weight prep in one kernel ----------------
__global__ __launch_bounds__(256) void k_prep_all(
    const float* __restrict__ c1w, const float* __restrict__ c2w,
    const float* __restrict__ qkv_w, const float* __restrict__ rel_table,
    const float* __restrict__ mlp_w1, const float* __restrict__ mlp_w2,
    const float* __restrict__ n2g, const float* __restrict__ n2b, const float* __restrict__ mb1,
    u16* __restrict__ Wpk1, u16* __restrict__ Wpk2, u16* __restrict__ Qkvpk,
    float* __restrict__ biasT, u16* __restrict__ W1pk, u16* __restrict__ W2pk,
    float* __restrict__ w1gd, float* __restrict__ wcv){
  int i = blockIdx.x*256 + threadIdx.x;
  if (i < 331776){
    int j = i & 7; int l = (i >> 3) & 63; int rem = i >> 9;
    int nt = rem % 12; int rem2 = rem / 12; int kc = rem2 % 6; int tap = rem2 / 6;
    int ci = kc*32 + ((l>>4)<<3) + j;
    int co = nt*16 + (l & 15);
    Wpk1[i] = f2b(c1w[(co*192 + ci)*9 + tap]);
    Wpk2[i] = f2b(c2w[(co*192 + ci)*9 + tap]);
    return;
  }
  i -= 331776;
  if (i < 110592){
    int j = i & 7; int l = (i >> 3) & 63; int rem = i >> 9;
    int kc = rem % 6; int nt = rem / 6;
    int row = nt*16 + (l & 15); int c = kc*32 + ((l>>4)<<3) + j;
    Qkvpk[i] = f2b(qkv_w[row*192 + c]);
    return;
  }
  i -= 110592;
  if (i < 24576){
    // biasT[h][k][q]
    int q = i & 63; int k = (i>>6) & 63; int h = i >> 12;
    int di = (q>>3) - (k>>3) + 7; int dj = (q&7) - (k&7) + 7;
    biasT[i] = rel_table[(di*15 + dj)*6 + h];
    return;
  }
  i -= 24576;
  if (i < 147456){
    // W1 pre-scaled by norm2 gamma (LN fold)
    int j = i & 7; int l = (i >> 3) & 63; int rem = i >> 9;
    int kc = rem % 6; int nt = rem / 6;
    int ho = nt*16 + (l & 15); int ci = kc*32 + ((l>>4)<<3) + j;
    W1pk[i] = f2b(mlp_w1[ho*192 + ci] * n2g[ci]);
    return;
  }
  i -= 147456;
  if (i < 147456){
    int j = i & 7; int l = (i >> 3) & 63; int rem = i >> 9;
    int kc = rem % 24; int nt = rem / 24;
    int co = nt*16 + (l & 15); int ho = kc*32 + ((l>>4)<<3) + j;
    W2pk[i] = f2b(mlp_w2[co*768 + ho]);
    return;
  }
  i -= 147456;
  if (i < 768){
    // dot-vectors for LN fold: w1gd = W1·g ; wcv = W1·b + mb1
    float sg = 0.f, sb = 0.f;
    const float* row = mlp_w1 + (size_t)i*192;
    for (int ci = 0; ci < 192; ++ci){ float w = row[ci]; sg += w*n2g[ci]; sb += w*n2b[ci]; }
    w1gd[i] = sg; wcv[i] = sb + mb1[i];
  }
}

// ---------------- fused LN1 + shifted-window attention (swapped QK^T, in-reg softmax) ----------------
__global__ __launch_bounds__(768, 3) void k_attn(const float* __restrict__ x, const u16* __restrict__ xn, int use_xn,
    const float* __restrict__ g1, const float* __restrict__ be1,
    const u16* __restrict__ qkvpk, const float* __restrict__ qkv_b,
    const float* __restrict__ biasT, u16* __restrict__ x1)
{
  __shared__ u16 xw[12800];            // [64][200]: input -> (after qkv) O staging
  __shared__ u16 qs[6][64][40];
  __shared__ u16 ks[6][64][40];
  __shared__ u16 vt[6][32][72];
  __shared__ int ih[64], iw[64], rid[64];
  __shared__ float red[64][12], red2[64][12], mu[64], rsg[64];
  int blk = blockIdx.x, t = threadIdx.x;
  int b = blk / NWIN, wi = blk % NWIN, wy = wi / 24, wx = wi % 24;
  int wid = t >> 6, l = t & 63, l15 = l & 15, lg = l >> 4;
  if (t < 64){
    int i = t >> 3, j = t & 7;
    int gh = wy*8 + i, gw = wx*8 + j;
    int hf = gh + 4; if (hf >= 192) hf -= 192;
    int wf = gw + 4; if (wf >= 192) wf -= 192;
    ih[t] = hf; iw[t] = wf;
    int rh = (gh < 184) ? 0 : ((gh < 188) ? 1 : 2);
    int rw = (gw < 184) ? 0 : ((gw < 188) ? 1 : 2);
    rid[t] = rh*3 + rw;
  }
  __syncthreads();
  // ---- load tokens ----
  if (use_xn){
    for (int idx = t; idx < 1536; idx += 768){
      int n = idx / 24, q = idx % 24;
      *(uint4*)&xw[n*200 + q*8] =
        *(const uint4*)(xn + ((size_t)((b*192 + ih[n])*192 + iw[n]))*192 + q*8);
    }
  } else {
    for (int idx = t; idx < 12288; idx += 768){
      int n = idx & 63, c = idx >> 6;
      xw[n*200 + c] = f2b(x[(((size_t)b*192 + c)*192 + ih[n])*192 + iw[n]]);
    }
  }
  __syncthreads();
  // ---- LN stats: 64 toks x 12 parts x 16ch ----
  { int n = t / 12, part = t % 12;
    float s = 0.f, s2 = 0.f;
    for (int c = part*16; c < part*16 + 16; ++c){ float v = b2f(xw[n*200 + c]); s += v; s2 += v*v; }
    red[n][part] = s; red2[n][part] = s2; }
  __syncthreads();
  if (t < 64){
    float s = 0.f, s2 = 0.f;
    #pragma unroll
    for (int p = 0; p < 12; ++p){ s += red[t][p]; s2 += red2[t][p]; }
    float m = s * (1.f/192.f);
    float v = s2 * (1.f/192.f) - m*m;
    mu[t] = m; rsg[t] = rsqrtf(v + 1e-5f);
  }
  __syncthreads();
  for (int idx = t; idx < 12288; idx += 768){
    int n = idx & 63, c = idx >> 6;
    float v = (b2f(xw[n*200 + c]) - mu[n]) * rsg[n] * g1[c] + be1[c];
    xw[n*200 + c] = f2b(v);
  }
  __syncthreads();
  // ---- qkv GEMM: wave wid owns n-tiles 3*wid .. 3*wid+2 of 36 ----
  {
    f32x4 acc[3][4];
    #pragma unroll
    for (int i3 = 0; i3 < 3; ++i3)
      #pragma unroll
      for (int mt = 0; mt < 4; ++mt) acc[i3][mt] = (f32x4){0.f,0.f,0.f,0.f};
    #pragma unroll
    for (int kc = 0; kc < 6; ++kc){
      bf16x8 a4[4];
      #pragma unroll
      for (int mt = 0; mt < 4; ++mt)
        a4[mt] = *(const bf16x8*)&xw[(mt*16 + l15)*200 + kc*32 + lg*8];
      #pragma unroll
      for (int i3 = 0; i3 < 3; ++i3){
        int ntg = wid*3 + i3;
        bf16x8 bf = *(const bf16x8*)(qkvpk + ((size_t)ntg*6 + kc)*512 + l*8);
        #pragma unroll
        for (int mt = 0; mt < 4; ++mt)
          acc[i3][mt] = mfma16(a4[mt], bf, acc[i3][mt]);
      }
    }
    #pragma unroll
    for (int i3 = 0; i3 < 3; ++i3){
      int ntg = wid*3 + i3;
      float bv = qkv_b[ntg*16 + l15];
      int m = ntg/12, hh = (ntg%12)>>1, hd0 = (ntg&1)*16;
      #pragma unroll
      for (int mt = 0; mt < 4; ++mt)
        #pragma unroll
        for (int r = 0; r < 4; ++r){
          int tok = mt*16 + lg*4 + r;
          float val = acc[i3][mt][r] + bv;
          if (m == 0){ qs[hh][tok][hd0 + l15] = f2b(val * ATT_SCALE); }
          else if (m == 1){ ks[hh][tok][hd0 + l15] = f2b(val); }
          else { vt[hh][hd0 + l15][tok] = f2b(val); }
        }
    }
  }
  __syncthreads();
  // ---- attention: wave = (head h, q-half mt0) ----
  int h = wid >> 1, mt0 = (wid & 1) * 2;
  // swapped QK^T: S^T frags, lane holds q = l15, k = nt*16 + lg*4 + r
  f32x4 st[2][4];
  {
    bf16x8 bq0 = *(const bf16x8*)&qs[h][(mt0  )*16 + l15][lg*8];
    bf16x8 bq1 = *(const bf16x8*)&qs[h][(mt0+1)*16 + l15][lg*8];
    #pragma unroll
    for (int nt = 0; nt < 4; ++nt){
      bf16x8 ak = *(const bf16x8*)&ks[h][nt*16 + l15][lg*8];
      st[0][nt] = mfma16(ak, bq0, (f32x4){0.f,0.f,0.f,0.f});
      st[1][nt] = mfma16(ak, bq1, (f32x4){0.f,0.f,0.f,0.f});
    }
  }
  // bias + mask + in-register softmax + pack to bf16 pairs
  u32 pk[2][4][2];
  #pragma unroll
  for (int m2 = 0; m2 < 2; ++m2){
    int qg = (mt0 + m2)*16 + l15;
    int rq = rid[qg];
    const float* bp = biasT + (size_t)h*4096 + qg;
    float mx = -1e30f;
    #pragma unroll
    for (int nt = 0; nt < 4; ++nt)
      #pragma unroll
      for (int r = 0; r < 4; ++r){
        int kg = nt*16 + lg*4 + r;
        float v = st[m2][nt][r] + bp[kg*64] + (rq != rid[kg] ? -100.f : 0.f);
        st[m2][nt][r] = v;
        mx = fmaxf(mx, v);
      }
    mx = fmaxf(mx, __shfl_xor(mx, 16));
    mx = fmaxf(mx, __shfl_xor(mx, 32));
    float ssum = 0.f;
    #pragma unroll
    for (int nt = 0; nt < 4; ++nt)
      #pragma unroll
      for (int r = 0; r < 4; ++r){
        float e = __expf(st[m2][nt][r] - mx);
        st[m2][nt][r] = e; ssum += e;
      }
    ssum += __shfl_xor(ssum, 16);
    ssum += __shfl_xor(ssum, 32);
    float inv = fast_rcp(ssum);
    #pragma unroll
    for (int nt = 0; nt < 4; ++nt){
      pk[m2][nt][0] = cvtpk(st[m2][nt][0]*inv, st[m2][nt][1]*inv);
      pk[m2][nt][1] = cvtpk(st[m2][nt][2]*inv, st[m2][nt][3]*inv);
    }
  }
  // PV: repack P via shfl into A-frags; B = V rows
  f32x4 o[2][2];
  #pragma unroll
  for (int m2 = 0; m2 < 2; ++m2)
    #pragma unroll
    for (int nd = 0; nd < 2; ++nd) o[m2][nd] = (f32x4){0.f,0.f,0.f,0.f};
  {
    int srcA = ((lg & 1) << 1)*16 + l15;
    bool hiSel = (lg & 2) != 0;
    #pragma unroll
    for (int kc = 0; kc < 2; ++kc){
      bf16x8 bv0 = *(const bf16x8*)&vt[h][l15][kc*32 + lg*8];
      bf16x8 bv1 = *(const bf16x8*)&vt[h][16 + l15][kc*32 + lg*8];
      #pragma unroll
      for (int m2 = 0; m2 < 2; ++m2){
        u32 q0 = __shfl((int)pk[m2][2*kc  ][0], srcA);
        u32 q1 = __shfl((int)pk[m2][2*kc+1][0], srcA);
        u32 q2 = __shfl((int)pk[m2][2*kc  ][1], srcA);
        u32 q3 = __shfl((int)pk[m2][2*kc+1][1], srcA);
        u32 q4 = __shfl((int)pk[m2][2*kc  ][0], srcA + 16);
        u32 q5 = __shfl((int)pk[m2][2*kc+1][0], srcA + 16);
        u32 q6 = __shfl((int)pk[m2][2*kc  ][1], srcA + 16);
        u32 q7 = __shfl((int)pk[m2][2*kc+1][1], srcA + 16);
        union { u32 u[4]; bf16x8 v; } ap;
        ap.u[0] = hiSel ? q1 : q0;
        ap.u[1] = hiSel ? q3 : q2;
        ap.u[2] = hiSel ? q5 : q4;
        ap.u[3] = hiSel ? q7 : q6;
        o[m2][0] = mfma16(ap.v, bv0, o[m2][0]);
        o[m2][1] = mfma16(ap.v, bv1, o[m2][1]);
      }
    }
  }
  // stage O into xw (input region dead after qkv barrier)
  #pragma unroll
  for (int m2 = 0; m2 < 2; ++m2)
    #pragma unroll
    for (int nd = 0; nd < 2; ++nd)
      #pragma unroll
      for (int r = 0; r < 4; ++r){
        int tok = (mt0 + m2)*16 + lg*4 + r;
        xw[tok*200 + h*32 + nd*16 + l15] = f2b(o[m2][nd][r]);
      }
  __syncthreads();
  // ---- residual add + store NHWC bf16 ----
  if (use_xn){
    for (int idx = t; idx < 1536; idx += 768){
      int n = idx / 24, q = idx % 24;
      size_t tokoff = (size_t)((b*192 + ih[n])*192 + iw[n]);
      uint4 xv = *(const uint4*)(xn + tokoff*192 + q*8);
      uint4 ov = *(const uint4*)&xw[n*200 + q*8];
      uint4 res;
      u32* xp = (u32*)&xv; u32* op = (u32*)&ov; u32* rp = (u32*)&res;
      #pragma unroll
      for (int w2 = 0; w2 < 4; ++w2){
        float a0 = b2f((u16)(xp[w2] & 0xffffu)) + b2f((u16)(op[w2] & 0xffffu));
        float a1 = b2f((u16)(xp[w2] >> 16))    + b2f((u16)(op[w2] >> 16));
        rp[w2] = (u32)f2b(a0) | ((u32)f2b(a1) << 16);
      }
      *(uint4*)(x1 + tokoff*192 + q*8) = res;
    }
  } else {
    for (int idx = t; idx < 12288; idx += 768){
      int n = idx & 63, c = idx >> 6;
      size_t tokoff = (size_t)((b*192 + ih[n])*192 + iw[n]);
      float sc = x[(((size_t)b*192 + c)*192 + ih[n])*192 + iw[n]];
      x1[tokoff*192 + c] = f2b(sc + b2f(xw[n*200 + c]));
    }
  }
}

// ---------------- depthwise 3x3 gate: x2 = x1 + dw(x1), 8-w tiles, XCD-swizzled ----------------
__global__ __launch_bounds__(192) void k_gate(const u16* __restrict__ x1, const float* __restrict__ gw,
                                              const float* __restrict__ gb, u16* __restrict__ x2){
  int bid = blockIdx.x;
  int blk = (bid & 7) * 2304 + (bid >> 3);   // 18432 = 8*2304: each XCD gets contiguous h-range
  int wt = blk % 24; int rem = blk / 24;
  int h = rem % 192; int b = rem / 192;
  int c = threadIdx.x;
  int w0 = wt*8;
  float wr[9];
  #pragma unroll
  for (int p = 0; p < 9; ++p) wr[p] = gw[c*9 + p];
  float bias = gb[c];
  float in[3][10];
  #pragma unroll
  for (int dy = 0; dy < 3; ++dy){
    int hh = h + dy - 1;
    bool hok = (hh >= 0 && hh < 192);
    #pragma unroll
    for (int p = 0; p < 10; ++p){
      int ww = w0 + p - 1;
      bool ok = hok && (ww >= 0 && ww < 192);
      in[dy][p] = ok ? b2f(x1[(((size_t)b*192 + hh)*192 + ww)*192 + c]) : 0.f;
    }
  }
  size_t rowbase = ((size_t)b*192 + h)*192;
  #pragma unroll
  for (int i = 0; i < 8; ++i){
    float acc = bias;
    #pragma unroll
    for (int dy = 0; dy < 3; ++dy)
      #pragma unroll
      for (int dx = 0; dx < 3; ++dx)
        acc += in[dy][i + dx] * wr[dy*3 + dx];
    float v = in[1][i + 1] + acc;
    x2[(rowbase + w0 + i)*192 + c] = f2b(v);
  }
}

// ---------------- 3x3 full conv, NHWC, MFMA implicit GEMM, 2 output rows/block, XCD-swizzled ----------------
__global__ __launch_bounds__(256) void k_conv(const u16* __restrict__ src, const u16* __restrict__ wpk,
                                              const float* __restrict__ cb, u16* __restrict__ dst,
                                              int do_gelu, float* __restrict__ pp){
  __shared__ u16 tin[27456];   // [4][66][104] ci-half tile; reused as obuf[128][200] (51.2KB)
  int bid = blockIdx.x;
  int blk = (bid & 7) * 144 + (bid >> 3);    // 1152 = 8*144: each XCD gets contiguous h-range
  int b = blk / 288; int rem = blk % 288;
  int hp = rem / 3; int w0 = (rem % 3) * 64;
  int h0 = hp*2;
  int t = threadIdx.x;
  int wid = t >> 6, l = t & 63;
  int l15 = l & 15, lg = l >> 4;
  f32x4 acc[8][3];
  #pragma unroll
  for (int mt = 0; mt < 8; ++mt)
    #pragma unroll
    for (int j = 0; j < 3; ++j) acc[mt][j] = (f32x4){0.f,0.f,0.f,0.f};
  for (int ch = 0; ch < 2; ++ch){
    __syncthreads();
    for (int idx = t; idx < 3168; idx += 256){
      int r = idx / 792; int r2 = idx % 792; int p = r2 / 12; int q = r2 % 12;
      int hh = h0 + r - 1, ww = w0 + p - 1;
      uint4 v = make_uint4(0u,0u,0u,0u);
      if (hh >= 0 && hh < 192 && ww >= 0 && ww < 192)
        v = *(const uint4*)(src + (((size_t)(b*192 + hh))*192 + ww)*192 + ch*96 + q*8);
      *(uint4*)&tin[(r*66 + p)*104 + q*8] = v;
    }
    __syncthreads();
    for (int dy = 0; dy < 3; ++dy){
      for (int kch = 0; kch < 3; ++kch){
        int kc = ch*3 + kch;
        #pragma unroll
        for (int dx = 0; dx < 3; ++dx){
          bf16x8 bw[3];
          #pragma unroll
          for (int j = 0; j < 3; ++j)
            bw[j] = *(const bf16x8*)(wpk + ((((size_t)(dy*3+dx)*6 + kc)*12 + wid*3 + j)*64 + l)*8);
          bf16x8 af[8];
          #pragma unroll
          for (int mt = 0; mt < 8; ++mt){
            int row = (mt >> 2) + dy;
            int p = (mt & 3)*16 + l15 + dx;
            af[mt] = *(const bf16x8*)&tin[(row*66 + p)*104 + kch*32 + lg*8];
          }
          __builtin_amdgcn_s_setprio(1);
          #pragma unroll
          for (int j = 0; j < 3; ++j)
            #pragma unroll
            for (int mt = 0; mt < 8; ++mt)
              acc[mt][j] = mfma16(af[mt], bw[j], acc[mt][j]);
          __builtin_amdgcn_s_setprio(0);
        }
      }
    }
  }
  __syncthreads();
  float bv[3];
  #pragma unroll
  for (int j = 0; j < 3; ++j) bv[j] = cb[wid*48 + j*16 + l15];
  #pragma unroll
  for (int mt = 0; mt < 8; ++mt)
    #pragma unroll
    for (int j = 0; j < 3; ++j)
      #pragma unroll
      for (int r = 0; r < 4; ++r){
        int px = mt*16 + lg*4 + r;
        float v = acc[mt][j][r] + bv[j];
        if (do_gelu) v = gelu_f(v);
        tin[px*200 + wid*48 + j*16 + l15] = f2b(v);
      }
  __syncthreads();
  for (int idx = t; idx < 3072; idx += 256){
    int px = idx / 24, q = idx % 24;
    *(uint4*)(dst + (((size_t)(b*192 + h0 + (px>>6)))*192 + w0 + (px & 63))*192 + q*8) =
      *(const uint4*)&tin[px*200 + q*8];
  }
  if (pp){
    // fused pool partial: sum over this block's 128 pixels per channel
    if (t < 192){
      float s = 0.f;
      #pragma unroll 8
      for (int px = 0; px < 128; ++px) s += b2f(tin[px*200 + t]);
      pp[(size_t)blk*192 + t] = s;
    }
  }
}

// ---------------- SE MLP (one block per batch; reduces 288 conv-block partials) ----------------
__global__ __launch_bounds__(256) void k_se(const float* __restrict__ pp, const float* __restrict__ w1,
    const float* __restrict__ bb1, const float* __restrict__ w2, const float* __restrict__ bb2,
    float* __restrict__ wgt){
  __shared__ float pb[192]; __shared__ float hq[12];
  int t = threadIdx.x;
  int b = blockIdx.x;
  if (t < 192){
    float s = 0.f;
    const float* base = pp + (size_t)b*288*192 + t;
    for (int ch = 0; ch < 288; ++ch) s += base[ch*192];
    pb[t] = s * (1.f/36864.f);
  }
  __syncthreads();
  if (t < 12){ float a = bb1[t]; for (int c = 0; c < 192; ++c) a += pb[c]*w1[t*192 + c]; hq[t] = fmaxf(a, 0.f); }
  __syncthreads();
  if (t < 192){ float a = bb2[t]; for (int m = 0; m < 12; ++m) a += hq[m]*w2[t*12 + m]; wgt[b*192 + t] = 1.f/(1.f + __expf(-a)); }
}

// ---------------- x3 = y2*wgt + x2 (fallback path only) ----------------
__global__ __launch_bounds__(256) void k_combine(const u16* __restrict__ y2, const u16* __restrict__ x2,
                                                 const float* __restrict__ wgt, u16* __restrict__ x3){
  size_t e = ((size_t)blockIdx.x*256 + threadIdx.x)*4;
  int c = (int)(e % 192);
  int b = (int)(e / ((size_t)SP*192));
  uint2 ya = *(const uint2*)(y2 + e);
  uint2 xa = *(const uint2*)(x2 + e);
  float4 wf = *(const float4*)(wgt + b*192 + c);
  float r0 = b2f((u16)(ya.x & 0xffffu))*wf.x + b2f((u16)(xa.x & 0xffffu));
  float r1 = b2f((u16)(ya.x >> 16))   *wf.y + b2f((u16)(xa.x >> 16));
  float r2 = b2f((u16)(ya.y & 0xffffu))*wf.z + b2f((u16)(xa.y & 0xffffu));
  float r3 = b2f((u16)(ya.y >> 16))   *wf.w + b2f((u16)(xa.y >> 16));
  uint2 o; o.x = (u32)f2b(r0) | ((u32)f2b(r1)<<16); o.y = (u32)f2b(r2) | ((u32)f2b(r3)<<16);
  *(uint2*)(x3 + e) = o;
}

// ---------------- fused [combine] + MLP with LN folded into W1 (MFMA, 32-tok, phased hidH) ----------------
__global__ __launch_bounds__(256, 2) void k_mlp(const u16* __restrict__ src0, const u16* __restrict__ src1,
    const float* __restrict__ wgt, int fused, const u16* __restrict__ W1pk,
    const float* __restrict__ w1gd, const float* __restrict__ wcv,
    const u16* __restrict__ W2pk, const float* __restrict__ mb2,
    float* __restrict__ out){
  __shared__ u16 lnS[32][200];         // raw combined x3 (NEVER overwritten)
  __shared__ u16 hidH[32*384];         // half-hidden [tok][ho'], rows 768B, byte ^= ((tok&7)<<4)
  __shared__ float mu[32], rsg[32];
  int blk = blockIdx.x, t = threadIdx.x;
  int b = blk / 1152; int rem = blk % 1152;
  int h = rem / 6; int w0 = (rem % 6) * 32;
  size_t tokbase = ((size_t)b*192 + h)*192 + w0;
  int wid = t >> 6, l = t & 63, l15 = l & 15, lg = l >> 4;
  char* hb = (char*)hidH;
  if (fused){
    for (int idx = t; idx < 768; idx += 256){
      int tok = idx / 24, q = idx % 24;
      uint4 yv = *(const uint4*)(src0 + (tokbase + tok)*192 + q*8);
      uint4 xv = *(const uint4*)(src1 + (tokbase + tok)*192 + q*8);
      const float* wb = wgt + b*192 + q*8;
      uint4 res;
      u32* yp = (u32*)&yv; u32* xp = (u32*)&xv; u32* rp = (u32*)&res;
      #pragma unroll
      for (int w2 = 0; w2 < 4; ++w2){
        float r0 = b2f((u16)(yp[w2] & 0xffffu))*wb[2*w2]   + b2f((u16)(xp[w2] & 0xffffu));
        float r1 = b2f((u16)(yp[w2] >> 16))   *wb[2*w2+1] + b2f((u16)(xp[w2] >> 16));
        rp[w2] = cvtpk(r0, r1);
      }
      *(uint4*)&lnS[tok][q*8] = res;
    }
  } else {
    for (int idx = t; idx < 768; idx += 256){
      int tok = idx / 24, q = idx % 24;
      *(uint4*)&lnS[tok][q*8] = *(const uint4*)(src0 + (tokbase + tok)*192 + q*8);
    }
  }
  __syncthreads();
  // stats: tok = t>>3, part = t&7; strided reads, 8-lane shfl reduce
  { int tok = t >> 3, part = t & 7;
    float s = 0.f, s2 = 0.f;
    #pragma unroll
    for (int i = 0; i < 3; ++i){
      uint4 v = *(const uint4*)&lnS[tok][part*8 + 64*i];
      u32* vp = (u32*)&v;
      #pragma unroll
      for (int q = 0; q < 4; ++q){
        float a = b2f((u16)(vp[q] & 0xffffu)), c2 = b2f((u16)(vp[q] >> 16));
        s += a + c2; s2 += a*a + c2*c2;
      }
    }
    #pragma unroll
    for (int d = 1; d < 8; d <<= 1){
      s  += __shfl_xor(s, d);
      s2 += __shfl_xor(s2, d);
    }
    if (part == 0){
      float m = s*(1.f/192.f); float v = s2*(1.f/192.f) - m*m;
      mu[tok] = m; rsg[tok] = rsqrtf(v + 1e-5f);
    } }
  __syncthreads();
  // per-lane LN scalars (tok = tt*16 + l15 is lane-constant in swapped GEMM1)
  float rsgL[2], rmuL[2];
  rsgL[0] = rsg[l15];      rmuL[0] = rsgL[0]*mu[l15];
  rsgL[1] = rsg[16 + l15]; rmuL[1] = rsgL[1]*mu[16 + l15];
  // preload raw-x3 B-frags once (reused both phases)
  bf16x8 bT[2][6];
  #pragma unroll
  for (int tt = 0; tt < 2; ++tt)
    #pragma unroll
    for (int kc = 0; kc < 6; ++kc)
      bT[tt][kc] = *(const bf16x8*)&lnS[tt*16 + l15][kc*32 + lg*8];
  int nb = wid*3;
  // two phases: GEMM1 half (ho' 384-wide) -> GEMM2 partial (kc 12); acc2 carried
  f32x4 acc2[2][3];
  #pragma unroll
  for (int mt = 0; mt < 2; ++mt)
    #pragma unroll
    for (int j = 0; j < 3; ++j) acc2[mt][j] = (f32x4){0.f,0.f,0.f,0.f};
  #pragma unroll
  for (int ph = 0; ph < 2; ++ph){
    // GEMM1: D[ho][tok] = W1g x x3^T; LN applied in epilogue via rsg/mu + dot-vectors
    #pragma unroll
    for (int i = 0; i < 6; ++i){
      int hot = ph*24 + wid*6 + i;
      bf16x8 aw[6];
      #pragma unroll
      for (int kc = 0; kc < 6; ++kc)
        aw[kc] = *(const bf16x8*)(W1pk + ((size_t)(hot*6 + kc)*64 + l)*8);
      float4 gd = *(const float4*)(w1gd + hot*16 + lg*4);
      float4 wc4 = *(const float4*)(wcv + hot*16 + lg*4);
      int hoL = (wid*6 + i)*16 + lg*4;    // local ho' in [0,384)
      #pragma unroll
      for (int tt = 0; tt < 2; ++tt){
        f32x4 acc = (f32x4){0.f,0.f,0.f,0.f};
        __builtin_amdgcn_s_setprio(1);
        #pragma unroll
        for (int kc = 0; kc < 6; ++kc)
          acc = mfma16(aw[kc], bT[tt][kc], acc);
        __builtin_amdgcn_s_setprio(0);
        float h0 = fmaf(rsgL[tt], acc[0], fmaf(-rmuL[tt], gd.x, wc4.x));
        float h1 = fmaf(rsgL[tt], acc[1], fmaf(-rmuL[tt], gd.y, wc4.y));
        float h2 = fmaf(rsgL[tt], acc[2], fmaf(-rmuL[tt], gd.z, wc4.z));
        float h3 = fmaf(rsgL[tt], acc[3], fmaf(-rmuL[tt], gd.w, wc4.w));
        u32 p0 = cvtpk(gelu_f(h0), gelu_f(h1));
        u32 p1 = cvtpk(gelu_f(h2), gelu_f(h3));
        int tok = tt*16 + l15;
        int byt = (tok*768 + hoL*2) ^ ((l15 & 7) << 4);
        *(uint2*)(hb + byt) = make_uint2(p0, p1);
      }
    }
    __syncthreads();
    // GEMM2 partial: local kc in [0,12), global k-chunk = ph*12 + kc
    #pragma unroll 2
    for (int kc = 0; kc < 12; ++kc){
      int by0 = ((      l15)*768 + (kc*32 + lg*8)*2) ^ ((l15 & 7) << 4);
      int by1 = ((16 +  l15)*768 + (kc*32 + lg*8)*2) ^ ((l15 & 7) << 4);
      bf16x8 a0 = *(const bf16x8*)(hb + by0);
      bf16x8 a1 = *(const bf16x8*)(hb + by1);
      bf16x8 bw3[3];
      #pragma unroll
      for (int j = 0; j < 3; ++j)
        bw3[j] = *(const bf16x8*)(W2pk + (((size_t)(nb + j)*24 + ph*12 + kc)*64 + l)*8);
      __builtin_amdgcn_s_setprio(1);
      #pragma unroll
      for (int j = 0; j < 3; ++j){
        acc2[0][j] = mfma16(a0, bw3[j], acc2[0][j]);
        acc2[1][j] = mfma16(a1, bw3[j], acc2[1][j]);
      }
      __builtin_amdgcn_s_setprio(0);
    }
    __syncthreads();
  }
  // epilogue: bias + residual (lnS intact), float4 stores to BCHW
  #pragma unroll
  for (int j = 0; j < 3; ++j){
    int co = (nb + j)*16 + l15;
    float bj = mb2[co];
    #pragma unroll
    for (int mt = 0; mt < 2; ++mt){
      int tok0 = mt*16 + lg*4;
      float4 ov;
      #pragma unroll
      for (int r = 0; r < 4; ++r)
        ((float*)&ov)[r] = b2f(lnS[tok0 + r][co]) + acc2[mt][j][r] + bj;
      *(float4*)(out + (((size_t)b*192 + co)*192 + h)*192 + w0 + tok0) = ov;
    }
  }
}

extern "C" void kernel_launch(void* const* d_in, const int* in_sizes, int n_in,
                              void* d_out, int out_size, void* d_ws, size_t ws_size,
                              hipStream_t stream){
  const float* x      = (const float*)d_in[0];
  const float* n1g    = (const float*)d_in[1];
  const float* n1b    = (const float*)d_in[2];
  const float* qkv_w  = (const float*)d_in[3];
  const float* qkv_b  = (const float*)d_in[4];
  const float* rel_t  = (const float*)d_in[5];
  const float* n2g    = (const float*)d_in[6];
  const float* n2b    = (const float*)d_in[7];
  const float* mlp_w1 = (const float*)d_in[8];
  const float* mlp_b1 = (const float*)d_in[9];
  const float* mlp_w2 = (const float*)d_in[10];
  const float* mlp_b2 = (const float*)d_in[11];
  const float* c1w    = (const float*)d_in[12];
  const float* c1b    = (const float*)d_in[13];
  const float* c2w    = (const float*)d_in[14];
  const float* c2b    = (const float*)d_in[15];
  const float* sew1   = (const float*)d_in[16];
  const float* seb1   = (const float*)d_in[17];
  const float* sew2   = (const float*)d_in[18];
  const float* seb2   = (const float*)d_in[19];
  const float* gw     = (const float*)d_in[20];
  const float* gb     = (const float*)d_in[21];

  const size_t E  = (size_t)4*192*192*192;
  const size_t EB = E*2;
  const size_t SMALL = 663552*2 + 221184 + 98304 + 294912*2 + 4*576*192*4 + 768*4*3 + 65536;
  char* ws = (char*)d_ws;
  u16* ws0 = (u16*)(ws);
  u16* ws1 = (u16*)(ws + EB);
  size_t off = 2*EB;
  int use_xn = (ws_size >= 3*EB + SMALL) ? 1 : 0;
  u16* xn = nullptr;
  if (use_xn){ xn = (u16*)(ws + off); off += EB; }
  u16* Wpk1  = (u16*)(ws + off); off += 663552;
  u16* Wpk2  = (u16*)(ws + off); off += 663552;
  u16* Qkvpk = (u16*)(ws + off); off += 221184;
  float* biasT = (float*)(ws + off); off += 98304;
  u16* W1pk = (u16*)(ws + off); off += 294912;
  u16* W2pk = (u16*)(ws + off); off += 294912;
  float* w1gd = (float*)(ws + off); off += 768*4;
  float* wcv  = (float*)(ws + off); off += 768*4;
  float* pp  = (float*)(ws + off); off += (size_t)4*576*192*4;
  float* wgt = (float*)(ws + off); off += 768*4;

  if (use_xn) k_transpose<<<6912, 256, 0, stream>>>(x, xn);
  k_prep_all<<<2979, 256, 0, stream>>>(c1w, c2w, qkv_w, rel_t, mlp_w1, mlp_w2,
                                       n2g, n2b, mlp_b1,
                                       Wpk1, Wpk2, Qkvpk, biasT, W1pk, W2pk, w1gd, wcv);

  k_attn<<<2304, 768, 0, stream>>>(x, xn, use_xn, n1g, n1b, Qkvpk, qkv_b, biasT, ws0);
  k_gate<<<18432, 192, 0, stream>>>(ws0, gw, gb, ws1);
  k_conv<<<1152, 256, 0, stream>>>(ws1, Wpk1, c1b, ws0, 1, nullptr);
  u16* y2 = use_xn ? xn : (u16*)d_out;
  k_conv<<<1152, 256, 0, stream>>>(ws0, Wpk2, c2b, y2, 0, pp);
  k_se<<<4, 256, 0, stream>>>(pp, sew1, seb1, sew2, seb2, wgt);
  if (use_xn){
    k_mlp<<<4608, 256, 0, stream>>>(y2, ws1, wgt, 1, W1pk, w1gd, wcv, W2pk, mlp_b2, (float*)d_out);
  } else {
    k_combine<<<27648, 256, 0, stream>>>((const u16*)d_out, ws1, wgt, ws0);
    k_mlp<<<4608, 256, 0, stream>>>(ws0, ws0, wgt, 0, W1pk, w1gd, wcv, W2pk, mlp_b2, (float*)d_out);
  }
}

// Round 15
// 582.878 us; speedup vs baseline: 1.0616x; 1.0616x over previous
//
#include <hip/hip_runtime.h>
#include <hip/hip_bf16.h>

#define NWIN 576
#define SP 36864
#define ATT_SCALE 0.17677669529663687f

typedef unsigned short u16;
typedef unsigned int u32;
typedef __attribute__((ext_vector_type(8))) __bf16 bf16x8;
typedef __attribute__((ext_vector_type(4))) float f32x4;

__device__ __forceinline__ float b2f(u16 u){ return __uint_as_float(((u32)u)<<16); }
__device__ __forceinline__ u16 f2b(float f){ u32 u = __float_as_uint(f); return (u16)((u + 0x7FFFu + ((u>>16)&1u)) >> 16); }
__device__ __forceinline__ float fast_rcp(float d){ float r; asm("v_rcp_f32 %0, %1" : "=v"(r) : "v"(d)); return r; }
__device__ __forceinline__ u32 cvtpk(float lo, float hi){ u32 r; asm("v_cvt_pk_bf16_f32 %0, %1, %2" : "=v"(r) : "v"(lo), "v"(hi)); return r; }
// tanh-form GELU: x*sigmoid(1.59577(x+0.044715x^3)); |err vs erf-GELU| <~1e-3
__device__ __forceinline__ float gelu_f(float v){
  float u = v*(1.5957691216f + 0.0713548163f*v*v);
  return v * fast_rcp(1.0f + __expf(-u));
}
__device__ __forceinline__ f32x4 mfma16(bf16x8 a, bf16x8 b, f32x4 c){
  return __builtin_amdgcn_mfma_f32_16x16x32_bf16(a, b, c, 0, 0, 0);
}

// ---------------- transpose BCHW fp32 -> NHWC bf16 (4 h-rows per block) ----------------
__global__ __launch_bounds__(256) void k_transpose(const float* __restrict__ x, u16* __restrict__ xn){
  __shared__ float tile[32][33];
  int blk = blockIdx.x;
  int b = blk / 1728; int rem = blk % 1728;
  int hg = rem / 36; int rem2 = rem % 36;
  int wt = rem2 / 6, ct = rem2 % 6;
  int t = threadIdx.x;
  int lw = t & 31, g = t >> 5;
  for (int r4 = 0; r4 < 4; ++r4){
    int h = hg*4 + r4;
    for (int r = 0; r < 4; ++r){
      int cl = g + r*8;
      tile[cl][lw] = x[(((size_t)b*192 + ct*32 + cl)*192 + h)*192 + wt*32 + lw];
    }
    __syncthreads();
    for (int r = 0; r < 4; ++r){
      int wl = g + r*8;
      xn[(((size_t)b*192 + h)*192 + wt*32 + wl)*192 + ct*32 + lw] = f2b(tile[lw][wl]);
    }
    __syncthreads();
  }
}

// ---------------- all weight prep in one kernel ----------------
__global__ __launch_bounds__(256) void k_prep_all(
    const float* __restrict__ c1w, const float* __restrict__ c2w,
    const float* __restrict__ qkv_w, const float* __restrict__ rel_table,
    const float* __restrict__ mlp_w1, const float* __restrict__ mlp_w2,
    const float* __restrict__ n2g, const float* __restrict__ n2b, const float* __restrict__ mb1,
    u16* __restrict__ Wpk1, u16* __restrict__ Wpk2, u16* __restrict__ Qkvpk,
    float* __restrict__ biasT, u16* __restrict__ W1pk, u16* __restrict__ W2pk,
    float* __restrict__ w1gd, float* __restrict__ wcv){
  int i = blockIdx.x*256 + threadIdx.x;
  if (i < 331776){
    int j = i & 7; int l = (i >> 3) & 63; int rem = i >> 9;
    int nt = rem % 12; int rem2 = rem / 12; int kc = rem2 % 6; int tap = rem2 / 6;
    int ci = kc*32 + ((l>>4)<<3) + j;
    int co = nt*16 + (l & 15);
    Wpk1[i] = f2b(c1w[(co*192 + ci)*9 + tap]);
    Wpk2[i] = f2b(c2w[(co*192 + ci)*9 + tap]);
    return;
  }
  i -= 331776;
  if (i < 110592){
    int j = i & 7; int l = (i >> 3) & 63; int rem = i >> 9;
    int kc = rem % 6; int nt = rem / 6;
    int row = nt*16 + (l & 15); int c = kc*32 + ((l>>4)<<3) + j;
    Qkvpk[i] = f2b(qkv_w[row*192 + c]);
    return;
  }
  i -= 110592;
  if (i < 24576){
    // biasT[h][k][q]
    int q = i & 63; int k = (i>>6) & 63; int h = i >> 12;
    int di = (q>>3) - (k>>3) + 7; int dj = (q&7) - (k&7) + 7;
    biasT[i] = rel_table[(di*15 + dj)*6 + h];
    return;
  }
  i -= 24576;
  if (i < 147456){
    // W1 pre-scaled by norm2 gamma (LN fold)
    int j = i & 7; int l = (i >> 3) & 63; int rem = i >> 9;
    int kc = rem % 6; int nt = rem / 6;
    int ho = nt*16 + (l & 15); int ci = kc*32 + ((l>>4)<<3) + j;
    W1pk[i] = f2b(mlp_w1[ho*192 + ci] * n2g[ci]);
    return;
  }
  i -= 147456;
  if (i < 147456){
    int j = i & 7; int l = (i >> 3) & 63; int rem = i >> 9;
    int kc = rem % 24; int nt = rem / 24;
    int co = nt*16 + (l & 15); int ho = kc*32 + ((l>>4)<<3) + j;
    W2pk[i] = f2b(mlp_w2[co*768 + ho]);
    return;
  }
  i -= 147456;
  if (i < 768){
    // dot-vectors for LN fold: w1gd = W1·g ; wcv = W1·b + mb1
    float sg = 0.f, sb = 0.f;
    const float* row = mlp_w1 + (size_t)i*192;
    for (int ci = 0; ci < 192; ++ci){ float w = row[ci]; sg += w*n2g[ci]; sb += w*n2b[ci]; }
    w1gd[i] = sg; wcv[i] = sb + mb1[i];
  }
}

// ---------------- fused LN1 + shifted-window attention (swapped QK^T, in-reg softmax) ----------------
__global__ __launch_bounds__(768, 3) void k_attn(const float* __restrict__ x, const u16* __restrict__ xn, int use_xn,
    const float* __restrict__ g1, const float* __restrict__ be1,
    const u16* __restrict__ qkvpk, const float* __restrict__ qkv_b,
    const float* __restrict__ biasT, u16* __restrict__ x1)
{
  __shared__ u16 xw[12800];            // [64][200]: input -> (after qkv) O staging
  __shared__ u16 qs[6][64][40];
  __shared__ u16 ks[6][64][40];
  __shared__ u16 vt[6][32][72];
  __shared__ int ih[64], iw[64], rid[64];
  __shared__ float red[64][12], red2[64][12], mu[64], rsg[64];
  int blk = blockIdx.x, t = threadIdx.x;
  int b = blk / NWIN, wi = blk % NWIN, wy = wi / 24, wx = wi % 24;
  int wid = t >> 6, l = t & 63, l15 = l & 15, lg = l >> 4;
  if (t < 64){
    int i = t >> 3, j = t & 7;
    int gh = wy*8 + i, gw = wx*8 + j;
    int hf = gh + 4; if (hf >= 192) hf -= 192;
    int wf = gw + 4; if (wf >= 192) wf -= 192;
    ih[t] = hf; iw[t] = wf;
    int rh = (gh < 184) ? 0 : ((gh < 188) ? 1 : 2);
    int rw = (gw < 184) ? 0 : ((gw < 188) ? 1 : 2);
    rid[t] = rh*3 + rw;
  }
  __syncthreads();
  // ---- load tokens ----
  if (use_xn){
    for (int idx = t; idx < 1536; idx += 768){
      int n = idx / 24, q = idx % 24;
      *(uint4*)&xw[n*200 + q*8] =
        *(const uint4*)(xn + ((size_t)((b*192 + ih[n])*192 + iw[n]))*192 + q*8);
    }
  } else {
    for (int idx = t; idx < 12288; idx += 768){
      int n = idx & 63, c = idx >> 6;
      xw[n*200 + c] = f2b(x[(((size_t)b*192 + c)*192 + ih[n])*192 + iw[n]]);
    }
  }
  __syncthreads();
  // ---- LN stats: 64 toks x 12 parts x 16ch ----
  { int n = t / 12, part = t % 12;
    float s = 0.f, s2 = 0.f;
    for (int c = part*16; c < part*16 + 16; ++c){ float v = b2f(xw[n*200 + c]); s += v; s2 += v*v; }
    red[n][part] = s; red2[n][part] = s2; }
  __syncthreads();
  if (t < 64){
    float s = 0.f, s2 = 0.f;
    #pragma unroll
    for (int p = 0; p < 12; ++p){ s += red[t][p]; s2 += red2[t][p]; }
    float m = s * (1.f/192.f);
    float v = s2 * (1.f/192.f) - m*m;
    mu[t] = m; rsg[t] = rsqrtf(v + 1e-5f);
  }
  __syncthreads();
  for (int idx = t; idx < 12288; idx += 768){
    int n = idx & 63, c = idx >> 6;
    float v = (b2f(xw[n*200 + c]) - mu[n]) * rsg[n] * g1[c] + be1[c];
    xw[n*200 + c] = f2b(v);
  }
  __syncthreads();
  // ---- qkv GEMM: wave wid owns n-tiles 3*wid .. 3*wid+2 of 36 ----
  {
    f32x4 acc[3][4];
    #pragma unroll
    for (int i3 = 0; i3 < 3; ++i3)
      #pragma unroll
      for (int mt = 0; mt < 4; ++mt) acc[i3][mt] = (f32x4){0.f,0.f,0.f,0.f};
    #pragma unroll
    for (int kc = 0; kc < 6; ++kc){
      bf16x8 a4[4];
      #pragma unroll
      for (int mt = 0; mt < 4; ++mt)
        a4[mt] = *(const bf16x8*)&xw[(mt*16 + l15)*200 + kc*32 + lg*8];
      #pragma unroll
      for (int i3 = 0; i3 < 3; ++i3){
        int ntg = wid*3 + i3;
        bf16x8 bf = *(const bf16x8*)(qkvpk + ((size_t)ntg*6 + kc)*512 + l*8);
        #pragma unroll
        for (int mt = 0; mt < 4; ++mt)
          acc[i3][mt] = mfma16(a4[mt], bf, acc[i3][mt]);
      }
    }
    #pragma unroll
    for (int i3 = 0; i3 < 3; ++i3){
      int ntg = wid*3 + i3;
      float bv = qkv_b[ntg*16 + l15];
      int m = ntg/12, hh = (ntg%12)>>1, hd0 = (ntg&1)*16;
      #pragma unroll
      for (int mt = 0; mt < 4; ++mt)
        #pragma unroll
        for (int r = 0; r < 4; ++r){
          int tok = mt*16 + lg*4 + r;
          float val = acc[i3][mt][r] + bv;
          if (m == 0){ qs[hh][tok][hd0 + l15] = f2b(val * ATT_SCALE); }
          else if (m == 1){ ks[hh][tok][hd0 + l15] = f2b(val); }
          else { vt[hh][hd0 + l15][tok] = f2b(val); }
        }
    }
  }
  __syncthreads();
  // ---- attention: wave = (head h, q-half mt0) ----
  int h = wid >> 1, mt0 = (wid & 1) * 2;
  // swapped QK^T: S^T frags, lane holds q = l15, k = nt*16 + lg*4 + r
  f32x4 st[2][4];
  {
    bf16x8 bq0 = *(const bf16x8*)&qs[h][(mt0  )*16 + l15][lg*8];
    bf16x8 bq1 = *(const bf16x8*)&qs[h][(mt0+1)*16 + l15][lg*8];
    #pragma unroll
    for (int nt = 0; nt < 4; ++nt){
      bf16x8 ak = *(const bf16x8*)&ks[h][nt*16 + l15][lg*8];
      st[0][nt] = mfma16(ak, bq0, (f32x4){0.f,0.f,0.f,0.f});
      st[1][nt] = mfma16(ak, bq1, (f32x4){0.f,0.f,0.f,0.f});
    }
  }
  // bias + mask + in-register softmax + pack to bf16 pairs
  u32 pk[2][4][2];
  #pragma unroll
  for (int m2 = 0; m2 < 2; ++m2){
    int qg = (mt0 + m2)*16 + l15;
    int rq = rid[qg];
    const float* bp = biasT + (size_t)h*4096 + qg;
    float mx = -1e30f;
    #pragma unroll
    for (int nt = 0; nt < 4; ++nt)
      #pragma unroll
      for (int r = 0; r < 4; ++r){
        int kg = nt*16 + lg*4 + r;
        float v = st[m2][nt][r] + bp[kg*64] + (rq != rid[kg] ? -100.f : 0.f);
        st[m2][nt][r] = v;
        mx = fmaxf(mx, v);
      }
    mx = fmaxf(mx, __shfl_xor(mx, 16));
    mx = fmaxf(mx, __shfl_xor(mx, 32));
    float ssum = 0.f;
    #pragma unroll
    for (int nt = 0; nt < 4; ++nt)
      #pragma unroll
      for (int r = 0; r < 4; ++r){
        float e = __expf(st[m2][nt][r] - mx);
        st[m2][nt][r] = e; ssum += e;
      }
    ssum += __shfl_xor(ssum, 16);
    ssum += __shfl_xor(ssum, 32);
    float inv = fast_rcp(ssum);
    #pragma unroll
    for (int nt = 0; nt < 4; ++nt){
      pk[m2][nt][0] = cvtpk(st[m2][nt][0]*inv, st[m2][nt][1]*inv);
      pk[m2][nt][1] = cvtpk(st[m2][nt][2]*inv, st[m2][nt][3]*inv);
    }
  }
  // PV: repack P via shfl into A-frags; B = V rows
  f32x4 o[2][2];
  #pragma unroll
  for (int m2 = 0; m2 < 2; ++m2)
    #pragma unroll
    for (int nd = 0; nd < 2; ++nd) o[m2][nd] = (f32x4){0.f,0.f,0.f,0.f};
  {
    int srcA = ((lg & 1) << 1)*16 + l15;
    bool hiSel = (lg & 2) != 0;
    #pragma unroll
    for (int kc = 0; kc < 2; ++kc){
      bf16x8 bv0 = *(const bf16x8*)&vt[h][l15][kc*32 + lg*8];
      bf16x8 bv1 = *(const bf16x8*)&vt[h][16 + l15][kc*32 + lg*8];
      #pragma unroll
      for (int m2 = 0; m2 < 2; ++m2){
        u32 q0 = __shfl((int)pk[m2][2*kc  ][0], srcA);
        u32 q1 = __shfl((int)pk[m2][2*kc+1][0], srcA);
        u32 q2 = __shfl((int)pk[m2][2*kc  ][1], srcA);
        u32 q3 = __shfl((int)pk[m2][2*kc+1][1], srcA);
        u32 q4 = __shfl((int)pk[m2][2*kc  ][0], srcA + 16);
        u32 q5 = __shfl((int)pk[m2][2*kc+1][0], srcA + 16);
        u32 q6 = __shfl((int)pk[m2][2*kc  ][1], srcA + 16);
        u32 q7 = __shfl((int)pk[m2][2*kc+1][1], srcA + 16);
        union { u32 u[4]; bf16x8 v; } ap;
        ap.u[0] = hiSel ? q1 : q0;
        ap.u[1] = hiSel ? q3 : q2;
        ap.u[2] = hiSel ? q5 : q4;
        ap.u[3] = hiSel ? q7 : q6;
        o[m2][0] = mfma16(ap.v, bv0, o[m2][0]);
        o[m2][1] = mfma16(ap.v, bv1, o[m2][1]);
      }
    }
  }
  // stage O into xw (input region dead after qkv barrier)
  #pragma unroll
  for (int m2 = 0; m2 < 2; ++m2)
    #pragma unroll
    for (int nd = 0; nd < 2; ++nd)
      #pragma unroll
      for (int r = 0; r < 4; ++r){
        int tok = (mt0 + m2)*16 + lg*4 + r;
        xw[tok*200 + h*32 + nd*16 + l15] = f2b(o[m2][nd][r]);
      }
  __syncthreads();
  // ---- residual add + store NHWC bf16 ----
  if (use_xn){
    for (int idx = t; idx < 1536; idx += 768){
      int n = idx / 24, q = idx % 24;
      size_t tokoff = (size_t)((b*192 + ih[n])*192 + iw[n]);
      uint4 xv = *(const uint4*)(xn + tokoff*192 + q*8);
      uint4 ov = *(const uint4*)&xw[n*200 + q*8];
      uint4 res;
      u32* xp = (u32*)&xv; u32* op = (u32*)&ov; u32* rp = (u32*)&res;
      #pragma unroll
      for (int w2 = 0; w2 < 4; ++w2){
        float a0 = b2f((u16)(xp[w2] & 0xffffu)) + b2f((u16)(op[w2] & 0xffffu));
        float a1 = b2f((u16)(xp[w2] >> 16))    + b2f((u16)(op[w2] >> 16));
        rp[w2] = (u32)f2b(a0) | ((u32)f2b(a1) << 16);
      }
      *(uint4*)(x1 + tokoff*192 + q*8) = res;
    }
  } else {
    for (int idx = t; idx < 12288; idx += 768){
      int n = idx & 63, c = idx >> 6;
      size_t tokoff = (size_t)((b*192 + ih[n])*192 + iw[n]);
      float sc = x[(((size_t)b*192 + c)*192 + ih[n])*192 + iw[n]];
      x1[tokoff*192 + c] = f2b(sc + b2f(xw[n*200 + c]));
    }
  }
}

// ---------------- depthwise 3x3 gate: x2 = x1 + dw(x1), 8-w tiles, XCD-swizzled ----------------
__global__ __launch_bounds__(192) void k_gate(const u16* __restrict__ x1, const float* __restrict__ gw,
                                              const float* __restrict__ gb, u16* __restrict__ x2){
  int bid = blockIdx.x;
  int blk = (bid & 7) * 2304 + (bid >> 3);   // 18432 = 8*2304: each XCD gets contiguous h-range
  int wt = blk % 24; int rem = blk / 24;
  int h = rem % 192; int b = rem / 192;
  int c = threadIdx.x;
  int w0 = wt*8;
  float wr[9];
  #pragma unroll
  for (int p = 0; p < 9; ++p) wr[p] = gw[c*9 + p];
  float bias = gb[c];
  float in[3][10];
  #pragma unroll
  for (int dy = 0; dy < 3; ++dy){
    int hh = h + dy - 1;
    bool hok = (hh >= 0 && hh < 192);
    #pragma unroll
    for (int p = 0; p < 10; ++p){
      int ww = w0 + p - 1;
      bool ok = hok && (ww >= 0 && ww < 192);
      in[dy][p] = ok ? b2f(x1[(((size_t)b*192 + hh)*192 + ww)*192 + c]) : 0.f;
    }
  }
  size_t rowbase = ((size_t)b*192 + h)*192;
  #pragma unroll
  for (int i = 0; i < 8; ++i){
    float acc = bias;
    #pragma unroll
    for (int dy = 0; dy < 3; ++dy)
      #pragma unroll
      for (int dx = 0; dx < 3; ++dx)
        acc += in[dy][i + dx] * wr[dy*3 + dx];
    float v = in[1][i + 1] + acc;
    x2[(rowbase + w0 + i)*192 + c] = f2b(v);
  }
}

// ---------------- 3x3 full conv, NHWC, MFMA implicit GEMM, XCD-swizzled, optional fused pool ----------------
__global__ __launch_bounds__(256) void k_conv(const u16* __restrict__ src, const u16* __restrict__ wpk,
                                              const float* __restrict__ cb, u16* __restrict__ dst,
                                              int do_gelu, float* __restrict__ pp){
  __shared__ u16 tin[20592];   // [3][66][104] ci-half tile; reused as obuf[64][200]
  int bid = blockIdx.x;
  int blk = (bid & 7) * 288 + (bid >> 3);    // 2304 = 8*288: each XCD gets contiguous h-range (halo L2-hits)
  int b = blk / 576; int rem = blk % 576;
  int h = rem / 3; int w0 = (rem % 3) * 64;
  int t = threadIdx.x;
  int wid = t >> 6, l = t & 63;
  int l15 = l & 15, lg = l >> 4;
  f32x4 acc[4][3];
  #pragma unroll
  for (int mt = 0; mt < 4; ++mt)
    #pragma unroll
    for (int j = 0; j < 3; ++j) acc[mt][j] = (f32x4){0.f,0.f,0.f,0.f};
  for (int ch = 0; ch < 2; ++ch){
    __syncthreads();
    for (int idx = t; idx < 2376; idx += 256){
      int r = idx / 792; int r2 = idx % 792; int p = r2 / 12; int q = r2 % 12;
      int hh = h + r - 1, ww = w0 + p - 1;
      uint4 v = make_uint4(0u,0u,0u,0u);
      if (hh >= 0 && hh < 192 && ww >= 0 && ww < 192)
        v = *(const uint4*)(src + (((size_t)(b*192 + hh))*192 + ww)*192 + ch*96 + q*8);
      *(uint4*)&tin[(r*66 + p)*104 + q*8] = v;
    }
    __syncthreads();
    for (int dy = 0; dy < 3; ++dy){
      for (int kch = 0; kch < 3; ++kch){
        bf16x8 af[4][3];
        #pragma unroll
        for (int mt = 0; mt < 4; ++mt)
          #pragma unroll
          for (int dx = 0; dx < 3; ++dx)
            af[mt][dx] = *(const bf16x8*)&tin[(dy*66 + mt*16 + l15 + dx)*104 + kch*32 + lg*8];
        bf16x8 bw[3][3];
        int kc = ch*3 + kch;
        #pragma unroll
        for (int dx = 0; dx < 3; ++dx)
          #pragma unroll
          for (int j = 0; j < 3; ++j)
            bw[dx][j] = *(const bf16x8*)(wpk + ((((size_t)(dy*3+dx)*6 + kc)*12 + wid*3 + j)*64 + l)*8);
        __builtin_amdgcn_s_setprio(1);
        #pragma unroll
        for (int dx = 0; dx < 3; ++dx)
          #pragma unroll
          for (int j = 0; j < 3; ++j)
            #pragma unroll
            for (int mt = 0; mt < 4; ++mt)
              acc[mt][j] = mfma16(af[mt][dx], bw[dx][j], acc[mt][j]);
        __builtin_amdgcn_s_setprio(0);
      }
    }
  }
  __syncthreads();
  float bv[3];
  #pragma unroll
  for (int j = 0; j < 3; ++j) bv[j] = cb[wid*48 + j*16 + l15];
  #pragma unroll
  for (int mt = 0; mt < 4; ++mt)
    #pragma unroll
    for (int j = 0; j < 3; ++j)
      #pragma unroll
      for (int r = 0; r < 4; ++r){
        int pix = mt*16 + lg*4 + r;
        float v = acc[mt][j][r] + bv[j];
        if (do_gelu) v = gelu_f(v);
        tin[pix*200 + wid*48 + j*16 + l15] = f2b(v);
      }
  __syncthreads();
  for (int idx = t; idx < 1536; idx += 256){
    int pix = idx / 24, q = idx % 24;
    *(uint4*)(dst + (((size_t)(b*192 + h))*192 + w0 + pix)*192 + q*8) = *(const uint4*)&tin[pix*200 + q*8];
  }
  if (pp){
    // fused pool partial: sum over this block's 64 pixels per channel
    if (t < 192){
      float s = 0.f;
      #pragma unroll 8
      for (int pix = 0; pix < 64; ++pix) s += b2f(tin[pix*200 + t]);
      pp[(size_t)blk*192 + t] = s;
    }
  }
}

// ---------------- SE MLP (one block per batch; reduces 576 conv-block partials) ----------------
__global__ __launch_bounds__(256) void k_se(const float* __restrict__ pp, const float* __restrict__ w1,
    const float* __restrict__ bb1, const float* __restrict__ w2, const float* __restrict__ bb2,
    float* __restrict__ wgt){
  __shared__ float pb[192]; __shared__ float hq[12];
  int t = threadIdx.x;
  int b = blockIdx.x;
  if (t < 192){
    float s = 0.f;
    const float* base = pp + (size_t)b*576*192 + t;
    for (int ch = 0; ch < 576; ++ch) s += base[ch*192];
    pb[t] = s * (1.f/36864.f);
  }
  __syncthreads();
  if (t < 12){ float a = bb1[t]; for (int c = 0; c < 192; ++c) a += pb[c]*w1[t*192 + c]; hq[t] = fmaxf(a, 0.f); }
  __syncthreads();
  if (t < 192){ float a = bb2[t]; for (int m = 0; m < 12; ++m) a += hq[m]*w2[t*12 + m]; wgt[b*192 + t] = 1.f/(1.f + __expf(-a)); }
}

// ---------------- x3 = y2*wgt + x2 (fallback path only) ----------------
__global__ __launch_bounds__(256) void k_combine(const u16* __restrict__ y2, const u16* __restrict__ x2,
                                                 const float* __restrict__ wgt, u16* __restrict__ x3){
  size_t e = ((size_t)blockIdx.x*256 + threadIdx.x)*4;
  int c = (int)(e % 192);
  int b = (int)(e / ((size_t)SP*192));
  uint2 ya = *(const uint2*)(y2 + e);
  uint2 xa = *(const uint2*)(x2 + e);
  float4 wf = *(const float4*)(wgt + b*192 + c);
  float r0 = b2f((u16)(ya.x & 0xffffu))*wf.x + b2f((u16)(xa.x & 0xffffu));
  float r1 = b2f((u16)(ya.x >> 16))   *wf.y + b2f((u16)(xa.x >> 16));
  float r2 = b2f((u16)(ya.y & 0xffffu))*wf.z + b2f((u16)(xa.y & 0xffffu));
  float r3 = b2f((u16)(ya.y >> 16))   *wf.w + b2f((u16)(xa.y >> 16));
  uint2 o; o.x = (u32)f2b(r0) | ((u32)f2b(r1)<<16); o.y = (u32)f2b(r2) | ((u32)f2b(r3)<<16);
  *(uint2*)(x3 + e) = o;
}

// ---------------- fused [combine] + MLP with LN folded into W1 (MFMA, 32-tok, phased hidH) ----------------
__global__ __launch_bounds__(256, 2) void k_mlp(const u16* __restrict__ src0, const u16* __restrict__ src1,
    const float* __restrict__ wgt, int fused, const u16* __restrict__ W1pk,
    const float* __restrict__ w1gd, const float* __restrict__ wcv,
    const u16* __restrict__ W2pk, const float* __restrict__ mb2,
    float* __restrict__ out){
  __shared__ u16 lnS[32][200];         // raw combined x3 (NEVER overwritten)
  __shared__ u16 hidH[32*384];         // half-hidden [tok][ho'], rows 768B, byte ^= ((tok&7)<<4)
  __shared__ float mu[32], rsg[32];
  int blk = blockIdx.x, t = threadIdx.x;
  int b = blk / 1152; int rem = blk % 1152;
  int h = rem / 6; int w0 = (rem % 6) * 32;
  size_t tokbase = ((size_t)b*192 + h)*192 + w0;
  int wid = t >> 6, l = t & 63, l15 = l & 15, lg = l >> 4;
  char* hb = (char*)hidH;
  if (fused){
    for (int idx = t; idx < 768; idx += 256){
      int tok = idx / 24, q = idx % 24;
      uint4 yv = *(const uint4*)(src0 + (tokbase + tok)*192 + q*8);
      uint4 xv = *(const uint4*)(src1 + (tokbase + tok)*192 + q*8);
      const float* wb = wgt + b*192 + q*8;
      uint4 res;
      u32* yp = (u32*)&yv; u32* xp = (u32*)&xv; u32* rp = (u32*)&res;
      #pragma unroll
      for (int w2 = 0; w2 < 4; ++w2){
        float r0 = b2f((u16)(yp[w2] & 0xffffu))*wb[2*w2]   + b2f((u16)(xp[w2] & 0xffffu));
        float r1 = b2f((u16)(yp[w2] >> 16))   *wb[2*w2+1] + b2f((u16)(xp[w2] >> 16));
        rp[w2] = cvtpk(r0, r1);
      }
      *(uint4*)&lnS[tok][q*8] = res;
    }
  } else {
    for (int idx = t; idx < 768; idx += 256){
      int tok = idx / 24, q = idx % 24;
      *(uint4*)&lnS[tok][q*8] = *(const uint4*)(src0 + (tokbase + tok)*192 + q*8);
    }
  }
  __syncthreads();
  // stats: tok = t>>3, part = t&7; strided reads, 8-lane shfl reduce
  { int tok = t >> 3, part = t & 7;
    float s = 0.f, s2 = 0.f;
    #pragma unroll
    for (int i = 0; i < 3; ++i){
      uint4 v = *(const uint4*)&lnS[tok][part*8 + 64*i];
      u32* vp = (u32*)&v;
      #pragma unroll
      for (int q = 0; q < 4; ++q){
        float a = b2f((u16)(vp[q] & 0xffffu)), c2 = b2f((u16)(vp[q] >> 16));
        s += a + c2; s2 += a*a + c2*c2;
      }
    }
    #pragma unroll
    for (int d = 1; d < 8; d <<= 1){
      s  += __shfl_xor(s, d);
      s2 += __shfl_xor(s2, d);
    }
    if (part == 0){
      float m = s*(1.f/192.f); float v = s2*(1.f/192.f) - m*m;
      mu[tok] = m; rsg[tok] = rsqrtf(v + 1e-5f);
    } }
  __syncthreads();
  // per-lane LN scalars (tok = tt*16 + l15 is lane-constant in swapped GEMM1)
  float rsgL[2], rmuL[2];
  rsgL[0] = rsg[l15];      rmuL[0] = rsgL[0]*mu[l15];
  rsgL[1] = rsg[16 + l15]; rmuL[1] = rsgL[1]*mu[16 + l15];
  // preload raw-x3 B-frags once (reused both phases)
  bf16x8 bT[2][6];
  #pragma unroll
  for (int tt = 0; tt < 2; ++tt)
    #pragma unroll
    for (int kc = 0; kc < 6; ++kc)
      bT[tt][kc] = *(const bf16x8*)&lnS[tt*16 + l15][kc*32 + lg*8];
  int nb = wid*3;
  // two phases: GEMM1 half (ho' 384-wide) -> GEMM2 partial (kc 12); acc2 carried
  f32x4 acc2[2][3];
  #pragma unroll
  for (int mt = 0; mt < 2; ++mt)
    #pragma unroll
    for (int j = 0; j < 3; ++j) acc2[mt][j] = (f32x4){0.f,0.f,0.f,0.f};
  #pragma unroll
  for (int ph = 0; ph < 2; ++ph){
    // GEMM1: D[ho][tok] = W1g x x3^T; LN applied in epilogue via rsg/mu + dot-vectors
    #pragma unroll
    for (int i = 0; i < 6; ++i){
      int hot = ph*24 + wid*6 + i;
      bf16x8 aw[6];
      #pragma unroll
      for (int kc = 0; kc < 6; ++kc)
        aw[kc] = *(const bf16x8*)(W1pk + ((size_t)(hot*6 + kc)*64 + l)*8);
      float4 gd = *(const float4*)(w1gd + hot*16 + lg*4);
      float4 wc4 = *(const float4*)(wcv + hot*16 + lg*4);
      int hoL = (wid*6 + i)*16 + lg*4;    // local ho' in [0,384)
      #pragma unroll
      for (int tt = 0; tt < 2; ++tt){
        f32x4 acc = (f32x4){0.f,0.f,0.f,0.f};
        __builtin_amdgcn_s_setprio(1);
        #pragma unroll
        for (int kc = 0; kc < 6; ++kc)
          acc = mfma16(aw[kc], bT[tt][kc], acc);
        __builtin_amdgcn_s_setprio(0);
        float h0 = fmaf(rsgL[tt], acc[0], fmaf(-rmuL[tt], gd.x, wc4.x));
        float h1 = fmaf(rsgL[tt], acc[1], fmaf(-rmuL[tt], gd.y, wc4.y));
        float h2 = fmaf(rsgL[tt], acc[2], fmaf(-rmuL[tt], gd.z, wc4.z));
        float h3 = fmaf(rsgL[tt], acc[3], fmaf(-rmuL[tt], gd.w, wc4.w));
        u32 p0 = cvtpk(gelu_f(h0), gelu_f(h1));
        u32 p1 = cvtpk(gelu_f(h2), gelu_f(h3));
        int tok = tt*16 + l15;
        int byt = (tok*768 + hoL*2) ^ ((l15 & 7) << 4);
        *(uint2*)(hb + byt) = make_uint2(p0, p1);
      }
    }
    __syncthreads();
    // GEMM2 partial: local kc in [0,12), global k-chunk = ph*12 + kc
    #pragma unroll 2
    for (int kc = 0; kc < 12; ++kc){
      int by0 = ((      l15)*768 + (kc*32 + lg*8)*2) ^ ((l15 & 7) << 4);
      int by1 = ((16 +  l15)*768 + (kc*32 + lg*8)*2) ^ ((l15 & 7) << 4);
      bf16x8 a0 = *(const bf16x8*)(hb + by0);
      bf16x8 a1 = *(const bf16x8*)(hb + by1);
      bf16x8 bw3[3];
      #pragma unroll
      for (int j = 0; j < 3; ++j)
        bw3[j] = *(const bf16x8*)(W2pk + (((size_t)(nb + j)*24 + ph*12 + kc)*64 + l)*8);
      __builtin_amdgcn_s_setprio(1);
      #pragma unroll
      for (int j = 0; j < 3; ++j){
        acc2[0][j] = mfma16(a0, bw3[j], acc2[0][j]);
        acc2[1][j] = mfma16(a1, bw3[j], acc2[1][j]);
      }
      __builtin_amdgcn_s_setprio(0);
    }
    __syncthreads();
  }
  // epilogue: bias + residual (lnS intact), float4 stores to BCHW
  #pragma unroll
  for (int j = 0; j < 3; ++j){
    int co = (nb + j)*16 + l15;
    float bj = mb2[co];
    #pragma unroll
    for (int mt = 0; mt < 2; ++mt){
      int tok0 = mt*16 + lg*4;
      float4 ov;
      #pragma unroll
      for (int r = 0; r < 4; ++r)
        ((float*)&ov)[r] = b2f(lnS[tok0 + r][co]) + acc2[mt][j][r] + bj;
      *(float4*)(out + (((size_t)b*192 + co)*192 + h)*192 + w0 + tok0) = ov;
    }
  }
}

extern "C" void kernel_launch(void* const* d_in, const int* in_sizes, int n_in,
                              void* d_out, int out_size, void* d_ws, size_t ws_size,
                              hipStream_t stream){
  const float* x      = (const float*)d_in[0];
  const float* n1g    = (const float*)d_in[1];
  const float* n1b    = (const float*)d_in[2];
  const float* qkv_w  = (const float*)d_in[3];
  const float* qkv_b  = (const float*)d_in[4];
  const float* rel_t  = (const float*)d_in[5];
  const float* n2g    = (const float*)d_in[6];
  const float* n2b    = (const float*)d_in[7];
  const float* mlp_w1 = (const float*)d_in[8];
  const float* mlp_b1 = (const float*)d_in[9];
  const float* mlp_w2 = (const float*)d_in[10];
  const float* mlp_b2 = (const float*)d_in[11];
  const float* c1w    = (const float*)d_in[12];
  const float* c1b    = (const float*)d_in[13];
  const float* c2w    = (const float*)d_in[14];
  const float* c2b    = (const float*)d_in[15];
  const float* sew1   = (const float*)d_in[16];
  const float* seb1   = (const float*)d_in[17];
  const float* sew2   = (const float*)d_in[18];
  const float* seb2   = (const float*)d_in[19];
  const float* gw     = (const float*)d_in[20];
  const float* gb     = (const float*)d_in[21];

  const size_t E  = (size_t)4*192*192*192;
  const size_t EB = E*2;
  const size_t SMALL = 663552*2 + 221184 + 98304 + 294912*2 + 4*576*192*4 + 768*4*3 + 65536;
  char* ws = (char*)d_ws;
  u16* ws0 = (u16*)(ws);
  u16* ws1 = (u16*)(ws + EB);
  size_t off = 2*EB;
  int use_xn = (ws_size >= 3*EB + SMALL) ? 1 : 0;
  u16* xn = nullptr;
  if (use_xn){ xn = (u16*)(ws + off); off += EB; }
  u16* Wpk1  = (u16*)(ws + off); off += 663552;
  u16* Wpk2  = (u16*)(ws + off); off += 663552;
  u16* Qkvpk = (u16*)(ws + off); off += 221184;
  float* biasT = (float*)(ws + off); off += 98304;
  u16* W1pk = (u16*)(ws + off); off += 294912;
  u16* W2pk = (u16*)(ws + off); off += 294912;
  float* w1gd = (float*)(ws + off); off += 768*4;
  float* wcv  = (float*)(ws + off); off += 768*4;
  float* pp  = (float*)(ws + off); off += (size_t)4*576*192*4;
  float* wgt = (float*)(ws + off); off += 768*4;

  if (use_xn) k_transpose<<<6912, 256, 0, stream>>>(x, xn);
  k_prep_all<<<2979, 256, 0, stream>>>(c1w, c2w, qkv_w, rel_t, mlp_w1, mlp_w2,
                                       n2g, n2b, mlp_b1,
                                       Wpk1, Wpk2, Qkvpk, biasT, W1pk, W2pk, w1gd, wcv);

  k_attn<<<2304, 768, 0, stream>>>(x, xn, use_xn, n1g, n1b, Qkvpk, qkv_b, biasT, ws0);
  k_gate<<<18432, 192, 0, stream>>>(ws0, gw, gb, ws1);
  k_conv<<<2304, 256, 0, stream>>>(ws1, Wpk1, c1b, ws0, 1, nullptr);
  u16* y2 = use_xn ? xn : (u16*)d_out;
  k_conv<<<2304, 256, 0, stream>>>(ws0, Wpk2, c2b, y2, 0, pp);
  k_se<<<4, 256, 0, stream>>>(pp, sew1, seb1, sew2, seb2, wgt);
  if (use_xn){
    k_mlp<<<4608, 256, 0, stream>>>(y2, ws1, wgt, 1, W1pk, w1gd, wcv, W2pk, mlp_b2, (float*)d_out);
  } else {
    k_combine<<<27648, 256, 0, stream>>>((const u16*)d_out, ws1, wgt, ws0);
    k_mlp<<<4608, 256, 0, stream>>>(ws0, ws0, wgt, 0, W1pk, w1gd, wcv, W2pk, mlp_b2, (float*)d_out);
  }
}

// Round 16
// 579.801 us; speedup vs baseline: 1.0673x; 1.0053x over previous
//
#include <hip/hip_runtime.h>
#include <hip/hip_bf16.h>

#define NWIN 576
#define SP 36864
#define ATT_SCALE 0.17677669529663687f

typedef unsigned short u16;
typedef unsigned int u32;
typedef __attribute__((ext_vector_type(8))) __bf16 bf16x8;
typedef __attribute__((ext_vector_type(4))) float f32x4;

__device__ __forceinline__ float b2f(u16 u){ return __uint_as_float(((u32)u)<<16); }
__device__ __forceinline__ u16 f2b(float f){ u32 u = __float_as_uint(f); return (u16)((u + 0x7FFFu + ((u>>16)&1u)) >> 16); }
__device__ __forceinline__ float fast_rcp(float d){ float r; asm("v_rcp_f32 %0, %1" : "=v"(r) : "v"(d)); return r; }
__device__ __forceinline__ u32 cvtpk(float lo, float hi){ u32 r; asm("v_cvt_pk_bf16_f32 %0, %1, %2" : "=v"(r) : "v"(lo), "v"(hi)); return r; }
// tanh-form GELU: x*sigmoid(1.59577(x+0.044715x^3)); |err vs erf-GELU| <~1e-3
__device__ __forceinline__ float gelu_f(float v){
  float u = v*(1.5957691216f + 0.0713548163f*v*v);
  return v * fast_rcp(1.0f + __expf(-u));
}
__device__ __forceinline__ f32x4 mfma16(bf16x8 a, bf16x8 b, f32x4 c){
  return __builtin_amdgcn_mfma_f32_16x16x32_bf16(a, b, c, 0, 0, 0);
}

// ---------------- transpose BCHW fp32 -> NHWC bf16 (4 h-rows per block) ----------------
__global__ __launch_bounds__(256) void k_transpose(const float* __restrict__ x, u16* __restrict__ xn){
  __shared__ float tile[32][33];
  int blk = blockIdx.x;
  int b = blk / 1728; int rem = blk % 1728;
  int hg = rem / 36; int rem2 = rem % 36;
  int wt = rem2 / 6, ct = rem2 % 6;
  int t = threadIdx.x;
  int lw = t & 31, g = t >> 5;
  for (int r4 = 0; r4 < 4; ++r4){
    int h = hg*4 + r4;
    for (int r = 0; r < 4; ++r){
      int cl = g + r*8;
      tile[cl][lw] = x[(((size_t)b*192 + ct*32 + cl)*192 + h)*192 + wt*32 + lw];
    }
    __syncthreads();
    for (int r = 0; r < 4; ++r){
      int wl = g + r*8;
      xn[(((size_t)b*192 + h)*192 + wt*32 + wl)*192 + ct*32 + lw] = f2b(tile[lw][wl]);
    }
    __syncthreads();
  }
}

// ---------------- all weight prep in one kernel ----------------
__global__ __launch_bounds__(256) void k_prep_all(
    const float* __restrict__ c1w, const float* __restrict__ c2w,
    const float* __restrict__ qkv_w, const float* __restrict__ rel_table,
    const float* __restrict__ mlp_w1, const float* __restrict__ mlp_w2,
    const float* __restrict__ n2g, const float* __restrict__ n2b, const float* __restrict__ mb1,
    u16* __restrict__ Wpk1, u16* __restrict__ Wpk2, u16* __restrict__ Qkvpk,
    float* __restrict__ biasT, u16* __restrict__ W1pk, u16* __restrict__ W2pk,
    float* __restrict__ w1gd, float* __restrict__ wcv){
  int i = blockIdx.x*256 + threadIdx.x;
  if (i < 331776){
    int j = i & 7; int l = (i >> 3) & 63; int rem = i >> 9;
    int nt = rem % 12; int rem2 = rem / 12; int kc = rem2 % 6; int tap = rem2 / 6;
    int ci = kc*32 + ((l>>4)<<3) + j;
    int co = nt*16 + (l & 15);
    Wpk1[i] = f2b(c1w[(co*192 + ci)*9 + tap]);
    Wpk2[i] = f2b(c2w[(co*192 + ci)*9 + tap]);
    return;
  }
  i -= 331776;
  if (i < 110592){
    int j = i & 7; int l = (i >> 3) & 63; int rem = i >> 9;
    int kc = rem % 6; int nt = rem / 6;
    int row = nt*16 + (l & 15); int c = kc*32 + ((l>>4)<<3) + j;
    Qkvpk[i] = f2b(qkv_w[row*192 + c]);
    return;
  }
  i -= 110592;
  if (i < 24576){
    // biasT[h][k][q]
    int q = i & 63; int k = (i>>6) & 63; int h = i >> 12;
    int di = (q>>3) - (k>>3) + 7; int dj = (q&7) - (k&7) + 7;
    biasT[i] = rel_table[(di*15 + dj)*6 + h];
    return;
  }
  i -= 24576;
  if (i < 147456){
    // W1 pre-scaled by norm2 gamma (LN fold)
    int j = i & 7; int l = (i >> 3) & 63; int rem = i >> 9;
    int kc = rem % 6; int nt = rem / 6;
    int ho = nt*16 + (l & 15); int ci = kc*32 + ((l>>4)<<3) + j;
    W1pk[i] = f2b(mlp_w1[ho*192 + ci] * n2g[ci]);
    return;
  }
  i -= 147456;
  if (i < 147456){
    int j = i & 7; int l = (i >> 3) & 63; int rem = i >> 9;
    int kc = rem % 24; int nt = rem / 24;
    int co = nt*16 + (l & 15); int ho = kc*32 + ((l>>4)<<3) + j;
    W2pk[i] = f2b(mlp_w2[co*768 + ho]);
    return;
  }
  i -= 147456;
  if (i < 768){
    // dot-vectors for LN fold: w1gd = W1·g ; wcv = W1·b + mb1
    float sg = 0.f, sb = 0.f;
    const float* row = mlp_w1 + (size_t)i*192;
    for (int ci = 0; ci < 192; ++ci){ float w = row[ci]; sg += w*n2g[ci]; sb += w*n2b[ci]; }
    w1gd[i] = sg; wcv[i] = sb + mb1[i];
  }
}

// ---------------- fused LN1 + shifted-window attention (swapped QK^T, in-reg softmax) ----------------
__global__ __launch_bounds__(768, 3) void k_attn(const float* __restrict__ x, const u16* __restrict__ xn, int use_xn,
    const float* __restrict__ g1, const float* __restrict__ be1,
    const u16* __restrict__ qkvpk, const float* __restrict__ qkv_b,
    const float* __restrict__ biasT, u16* __restrict__ x1)
{
  __shared__ u16 xw[12800];            // [64][200]: input -> (after qkv) O staging
  __shared__ u16 qs[6][64][40];
  __shared__ u16 ks[6][64][40];
  __shared__ u16 vt[6][32][72];
  __shared__ int ih[64], iw[64], rid[64];
  __shared__ float red[64][12], red2[64][12], mu[64], rsg[64];
  int blk = blockIdx.x, t = threadIdx.x;
  int b = blk / NWIN, wi = blk % NWIN, wy = wi / 24, wx = wi % 24;
  int wid = t >> 6, l = t & 63, l15 = l & 15, lg = l >> 4;
  if (t < 64){
    int i = t >> 3, j = t & 7;
    int gh = wy*8 + i, gw = wx*8 + j;
    int hf = gh + 4; if (hf >= 192) hf -= 192;
    int wf = gw + 4; if (wf >= 192) wf -= 192;
    ih[t] = hf; iw[t] = wf;
    int rh = (gh < 184) ? 0 : ((gh < 188) ? 1 : 2);
    int rw = (gw < 184) ? 0 : ((gw < 188) ? 1 : 2);
    rid[t] = rh*3 + rw;
  }
  __syncthreads();
  // ---- load tokens ----
  if (use_xn){
    for (int idx = t; idx < 1536; idx += 768){
      int n = idx / 24, q = idx % 24;
      *(uint4*)&xw[n*200 + q*8] =
        *(const uint4*)(xn + ((size_t)((b*192 + ih[n])*192 + iw[n]))*192 + q*8);
    }
  } else {
    for (int idx = t; idx < 12288; idx += 768){
      int n = idx & 63, c = idx >> 6;
      xw[n*200 + c] = f2b(x[(((size_t)b*192 + c)*192 + ih[n])*192 + iw[n]]);
    }
  }
  __syncthreads();
  // ---- LN stats: 64 toks x 12 parts x 16ch ----
  { int n = t / 12, part = t % 12;
    float s = 0.f, s2 = 0.f;
    for (int c = part*16; c < part*16 + 16; ++c){ float v = b2f(xw[n*200 + c]); s += v; s2 += v*v; }
    red[n][part] = s; red2[n][part] = s2; }
  __syncthreads();
  if (t < 64){
    float s = 0.f, s2 = 0.f;
    #pragma unroll
    for (int p = 0; p < 12; ++p){ s += red[t][p]; s2 += red2[t][p]; }
    float m = s * (1.f/192.f);
    float v = s2 * (1.f/192.f) - m*m;
    mu[t] = m; rsg[t] = rsqrtf(v + 1e-5f);
  }
  __syncthreads();
  for (int idx = t; idx < 12288; idx += 768){
    int n = idx & 63, c = idx >> 6;
    float v = (b2f(xw[n*200 + c]) - mu[n]) * rsg[n] * g1[c] + be1[c];
    xw[n*200 + c] = f2b(v);
  }
  __syncthreads();
  // ---- qkv GEMM: wave wid owns n-tiles 3*wid .. 3*wid+2 of 36 ----
  {
    f32x4 acc[3][4];
    #pragma unroll
    for (int i3 = 0; i3 < 3; ++i3)
      #pragma unroll
      for (int mt = 0; mt < 4; ++mt) acc[i3][mt] = (f32x4){0.f,0.f,0.f,0.f};
    #pragma unroll
    for (int kc = 0; kc < 6; ++kc){
      bf16x8 a4[4];
      #pragma unroll
      for (int mt = 0; mt < 4; ++mt)
        a4[mt] = *(const bf16x8*)&xw[(mt*16 + l15)*200 + kc*32 + lg*8];
      #pragma unroll
      for (int i3 = 0; i3 < 3; ++i3){
        int ntg = wid*3 + i3;
        bf16x8 bf = *(const bf16x8*)(qkvpk + ((size_t)ntg*6 + kc)*512 + l*8);
        #pragma unroll
        for (int mt = 0; mt < 4; ++mt)
          acc[i3][mt] = mfma16(a4[mt], bf, acc[i3][mt]);
      }
    }
    #pragma unroll
    for (int i3 = 0; i3 < 3; ++i3){
      int ntg = wid*3 + i3;
      float bv = qkv_b[ntg*16 + l15];
      int m = ntg/12, hh = (ntg%12)>>1, hd0 = (ntg&1)*16;
      #pragma unroll
      for (int mt = 0; mt < 4; ++mt)
        #pragma unroll
        for (int r = 0; r < 4; ++r){
          int tok = mt*16 + lg*4 + r;
          float val = acc[i3][mt][r] + bv;
          if (m == 0){ qs[hh][tok][hd0 + l15] = f2b(val * ATT_SCALE); }
          else if (m == 1){ ks[hh][tok][hd0 + l15] = f2b(val); }
          else { vt[hh][hd0 + l15][tok] = f2b(val); }
        }
    }
  }
  __syncthreads();
  // ---- attention: wave = (head h, q-half mt0) ----
  int h = wid >> 1, mt0 = (wid & 1) * 2;
  // swapped QK^T: S^T frags, lane holds q = l15, k = nt*16 + lg*4 + r
  f32x4 st[2][4];
  {
    bf16x8 bq0 = *(const bf16x8*)&qs[h][(mt0  )*16 + l15][lg*8];
    bf16x8 bq1 = *(const bf16x8*)&qs[h][(mt0+1)*16 + l15][lg*8];
    #pragma unroll
    for (int nt = 0; nt < 4; ++nt){
      bf16x8 ak = *(const bf16x8*)&ks[h][nt*16 + l15][lg*8];
      st[0][nt] = mfma16(ak, bq0, (f32x4){0.f,0.f,0.f,0.f});
      st[1][nt] = mfma16(ak, bq1, (f32x4){0.f,0.f,0.f,0.f});
    }
  }
  // bias + mask + in-register softmax + pack to bf16 pairs
  u32 pk[2][4][2];
  #pragma unroll
  for (int m2 = 0; m2 < 2; ++m2){
    int qg = (mt0 + m2)*16 + l15;
    int rq = rid[qg];
    const float* bp = biasT + (size_t)h*4096 + qg;
    float mx = -1e30f;
    #pragma unroll
    for (int nt = 0; nt < 4; ++nt)
      #pragma unroll
      for (int r = 0; r < 4; ++r){
        int kg = nt*16 + lg*4 + r;
        float v = st[m2][nt][r] + bp[kg*64] + (rq != rid[kg] ? -100.f : 0.f);
        st[m2][nt][r] = v;
        mx = fmaxf(mx, v);
      }
    mx = fmaxf(mx, __shfl_xor(mx, 16));
    mx = fmaxf(mx, __shfl_xor(mx, 32));
    float ssum = 0.f;
    #pragma unroll
    for (int nt = 0; nt < 4; ++nt)
      #pragma unroll
      for (int r = 0; r < 4; ++r){
        float e = __expf(st[m2][nt][r] - mx);
        st[m2][nt][r] = e; ssum += e;
      }
    ssum += __shfl_xor(ssum, 16);
    ssum += __shfl_xor(ssum, 32);
    float inv = fast_rcp(ssum);
    #pragma unroll
    for (int nt = 0; nt < 4; ++nt){
      pk[m2][nt][0] = cvtpk(st[m2][nt][0]*inv, st[m2][nt][1]*inv);
      pk[m2][nt][1] = cvtpk(st[m2][nt][2]*inv, st[m2][nt][3]*inv);
    }
  }
  // PV: repack P via shfl into A-frags; B = V rows
  f32x4 o[2][2];
  #pragma unroll
  for (int m2 = 0; m2 < 2; ++m2)
    #pragma unroll
    for (int nd = 0; nd < 2; ++nd) o[m2][nd] = (f32x4){0.f,0.f,0.f,0.f};
  {
    int srcA = ((lg & 1) << 1)*16 + l15;
    bool hiSel = (lg & 2) != 0;
    #pragma unroll
    for (int kc = 0; kc < 2; ++kc){
      bf16x8 bv0 = *(const bf16x8*)&vt[h][l15][kc*32 + lg*8];
      bf16x8 bv1 = *(const bf16x8*)&vt[h][16 + l15][kc*32 + lg*8];
      #pragma unroll
      for (int m2 = 0; m2 < 2; ++m2){
        u32 q0 = __shfl((int)pk[m2][2*kc  ][0], srcA);
        u32 q1 = __shfl((int)pk[m2][2*kc+1][0], srcA);
        u32 q2 = __shfl((int)pk[m2][2*kc  ][1], srcA);
        u32 q3 = __shfl((int)pk[m2][2*kc+1][1], srcA);
        u32 q4 = __shfl((int)pk[m2][2*kc  ][0], srcA + 16);
        u32 q5 = __shfl((int)pk[m2][2*kc+1][0], srcA + 16);
        u32 q6 = __shfl((int)pk[m2][2*kc  ][1], srcA + 16);
        u32 q7 = __shfl((int)pk[m2][2*kc+1][1], srcA + 16);
        union { u32 u[4]; bf16x8 v; } ap;
        ap.u[0] = hiSel ? q1 : q0;
        ap.u[1] = hiSel ? q3 : q2;
        ap.u[2] = hiSel ? q5 : q4;
        ap.u[3] = hiSel ? q7 : q6;
        o[m2][0] = mfma16(ap.v, bv0, o[m2][0]);
        o[m2][1] = mfma16(ap.v, bv1, o[m2][1]);
      }
    }
  }
  // stage O into xw (input region dead after qkv barrier)
  #pragma unroll
  for (int m2 = 0; m2 < 2; ++m2)
    #pragma unroll
    for (int nd = 0; nd < 2; ++nd)
      #pragma unroll
      for (int r = 0; r < 4; ++r){
        int tok = (mt0 + m2)*16 + lg*4 + r;
        xw[tok*200 + h*32 + nd*16 + l15] = f2b(o[m2][nd][r]);
      }
  __syncthreads();
  // ---- residual add + store NHWC bf16 ----
  if (use_xn){
    for (int idx = t; idx < 1536; idx += 768){
      int n = idx / 24, q = idx % 24;
      size_t tokoff = (size_t)((b*192 + ih[n])*192 + iw[n]);
      uint4 xv = *(const uint4*)(xn + tokoff*192 + q*8);
      uint4 ov = *(const uint4*)&xw[n*200 + q*8];
      uint4 res;
      u32* xp = (u32*)&xv; u32* op = (u32*)&ov; u32* rp = (u32*)&res;
      #pragma unroll
      for (int w2 = 0; w2 < 4; ++w2){
        float a0 = b2f((u16)(xp[w2] & 0xffffu)) + b2f((u16)(op[w2] & 0xffffu));
        float a1 = b2f((u16)(xp[w2] >> 16))    + b2f((u16)(op[w2] >> 16));
        rp[w2] = (u32)f2b(a0) | ((u32)f2b(a1) << 16);
      }
      *(uint4*)(x1 + tokoff*192 + q*8) = res;
    }
  } else {
    for (int idx = t; idx < 12288; idx += 768){
      int n = idx & 63, c = idx >> 6;
      size_t tokoff = (size_t)((b*192 + ih[n])*192 + iw[n]);
      float sc = x[(((size_t)b*192 + c)*192 + ih[n])*192 + iw[n]];
      x1[tokoff*192 + c] = f2b(sc + b2f(xw[n*200 + c]));
    }
  }
}

// ---------------- depthwise 3x3 gate: x2 = x1 + dw(x1), 8-w tiles, XCD-swizzled ----------------
__global__ __launch_bounds__(192) void k_gate(const u16* __restrict__ x1, const float* __restrict__ gw,
                                              const float* __restrict__ gb, u16* __restrict__ x2){
  int bid = blockIdx.x;
  int blk = (bid & 7) * 2304 + (bid >> 3);   // 18432 = 8*2304: each XCD gets contiguous h-range
  int wt = blk % 24; int rem = blk / 24;
  int h = rem % 192; int b = rem / 192;
  int c = threadIdx.x;
  int w0 = wt*8;
  float wr[9];
  #pragma unroll
  for (int p = 0; p < 9; ++p) wr[p] = gw[c*9 + p];
  float bias = gb[c];
  float in[3][10];
  #pragma unroll
  for (int dy = 0; dy < 3; ++dy){
    int hh = h + dy - 1;
    bool hok = (hh >= 0 && hh < 192);
    #pragma unroll
    for (int p = 0; p < 10; ++p){
      int ww = w0 + p - 1;
      bool ok = hok && (ww >= 0 && ww < 192);
      in[dy][p] = ok ? b2f(x1[(((size_t)b*192 + hh)*192 + ww)*192 + c]) : 0.f;
    }
  }
  size_t rowbase = ((size_t)b*192 + h)*192;
  #pragma unroll
  for (int i = 0; i < 8; ++i){
    float acc = bias;
    #pragma unroll
    for (int dy = 0; dy < 3; ++dy)
      #pragma unroll
      for (int dx = 0; dx < 3; ++dx)
        acc += in[dy][i + dx] * wr[dy*3 + dx];
    float v = in[1][i + 1] + acc;
    x2[(rowbase + w0 + i)*192 + c] = f2b(v);
  }
}

// ---------------- 3x3 full conv, NHWC, MFMA implicit GEMM, XCD-swizzled, optional fused pool ----------------
__global__ __launch_bounds__(256) void k_conv(const u16* __restrict__ src, const u16* __restrict__ wpk,
                                              const float* __restrict__ cb, u16* __restrict__ dst,
                                              int do_gelu, float* __restrict__ pp){
  __shared__ u16 tin[20592];   // [3][66][104] ci-half tile; reused as obuf[64][200]
  int bid = blockIdx.x;
  int blk = (bid & 7) * 288 + (bid >> 3);    // 2304 = 8*288: each XCD gets contiguous h-range (halo L2-hits)
  int b = blk / 576; int rem = blk % 576;
  int h = rem / 3; int w0 = (rem % 3) * 64;
  int t = threadIdx.x;
  int wid = t >> 6, l = t & 63;
  int l15 = l & 15, lg = l >> 4;
  f32x4 acc[4][3];
  #pragma unroll
  for (int mt = 0; mt < 4; ++mt)
    #pragma unroll
    for (int j = 0; j < 3; ++j) acc[mt][j] = (f32x4){0.f,0.f,0.f,0.f};
  for (int ch = 0; ch < 2; ++ch){
    __syncthreads();
    for (int idx = t; idx < 2376; idx += 256){
      int r = idx / 792; int r2 = idx % 792; int p = r2 / 12; int q = r2 % 12;
      int hh = h + r - 1, ww = w0 + p - 1;
      uint4 v = make_uint4(0u,0u,0u,0u);
      if (hh >= 0 && hh < 192 && ww >= 0 && ww < 192)
        v = *(const uint4*)(src + (((size_t)(b*192 + hh))*192 + ww)*192 + ch*96 + q*8);
      *(uint4*)&tin[(r*66 + p)*104 + q*8] = v;
    }
    __syncthreads();
    for (int dy = 0; dy < 3; ++dy){
      for (int kch = 0; kch < 3; ++kch){
        bf16x8 af[4][3];
        #pragma unroll
        for (int mt = 0; mt < 4; ++mt)
          #pragma unroll
          for (int dx = 0; dx < 3; ++dx)
            af[mt][dx] = *(const bf16x8*)&tin[(dy*66 + mt*16 + l15 + dx)*104 + kch*32 + lg*8];
        bf16x8 bw[3][3];
        int kc = ch*3 + kch;
        #pragma unroll
        for (int dx = 0; dx < 3; ++dx)
          #pragma unroll
          for (int j = 0; j < 3; ++j)
            bw[dx][j] = *(const bf16x8*)(wpk + ((((size_t)(dy*3+dx)*6 + kc)*12 + wid*3 + j)*64 + l)*8);
        __builtin_amdgcn_s_setprio(1);
        #pragma unroll
        for (int dx = 0; dx < 3; ++dx)
          #pragma unroll
          for (int j = 0; j < 3; ++j)
            #pragma unroll
            for (int mt = 0; mt < 4; ++mt)
              acc[mt][j] = mfma16(af[mt][dx], bw[dx][j], acc[mt][j]);
        __builtin_amdgcn_s_setprio(0);
      }
    }
  }
  __syncthreads();
  float bv[3];
  #pragma unroll
  for (int j = 0; j < 3; ++j) bv[j] = cb[wid*48 + j*16 + l15];
  #pragma unroll
  for (int mt = 0; mt < 4; ++mt)
    #pragma unroll
    for (int j = 0; j < 3; ++j)
      #pragma unroll
      for (int r = 0; r < 4; ++r){
        int pix = mt*16 + lg*4 + r;
        float v = acc[mt][j][r] + bv[j];
        if (do_gelu) v = gelu_f(v);
        tin[pix*200 + wid*48 + j*16 + l15] = f2b(v);
      }
  __syncthreads();
  for (int idx = t; idx < 1536; idx += 256){
    int pix = idx / 24, q = idx % 24;
    *(uint4*)(dst + (((size_t)(b*192 + h))*192 + w0 + pix)*192 + q*8) = *(const uint4*)&tin[pix*200 + q*8];
  }
  if (pp){
    // fused pool partial: sum over this block's 64 pixels per channel
    if (t < 192){
      float s = 0.f;
      #pragma unroll 8
      for (int pix = 0; pix < 64; ++pix) s += b2f(tin[pix*200 + t]);
      pp[(size_t)blk*192 + t] = s;
    }
  }
}

// ---------------- SE MLP (one block per batch; reduces 576 conv-block partials) ----------------
__global__ __launch_bounds__(256) void k_se(const float* __restrict__ pp, const float* __restrict__ w1,
    const float* __restrict__ bb1, const float* __restrict__ w2, const float* __restrict__ bb2,
    float* __restrict__ wgt){
  __shared__ float pb[192]; __shared__ float hq[12];
  int t = threadIdx.x;
  int b = blockIdx.x;
  if (t < 192){
    float s = 0.f;
    const float* base = pp + (size_t)b*576*192 + t;
    for (int ch = 0; ch < 576; ++ch) s += base[ch*192];
    pb[t] = s * (1.f/36864.f);
  }
  __syncthreads();
  if (t < 12){ float a = bb1[t]; for (int c = 0; c < 192; ++c) a += pb[c]*w1[t*192 + c]; hq[t] = fmaxf(a, 0.f); }
  __syncthreads();
  if (t < 192){ float a = bb2[t]; for (int m = 0; m < 12; ++m) a += hq[m]*w2[t*12 + m]; wgt[b*192 + t] = 1.f/(1.f + __expf(-a)); }
}

// ---------------- x3 = y2*wgt + x2 (fallback path only) ----------------
__global__ __launch_bounds__(256) void k_combine(const u16* __restrict__ y2, const u16* __restrict__ x2,
                                                 const float* __restrict__ wgt, u16* __restrict__ x3){
  size_t e = ((size_t)blockIdx.x*256 + threadIdx.x)*4;
  int c = (int)(e % 192);
  int b = (int)(e / ((size_t)SP*192));
  uint2 ya = *(const uint2*)(y2 + e);
  uint2 xa = *(const uint2*)(x2 + e);
  float4 wf = *(const float4*)(wgt + b*192 + c);
  float r0 = b2f((u16)(ya.x & 0xffffu))*wf.x + b2f((u16)(xa.x & 0xffffu));
  float r1 = b2f((u16)(ya.x >> 16))   *wf.y + b2f((u16)(xa.x >> 16));
  float r2 = b2f((u16)(ya.y & 0xffffu))*wf.z + b2f((u16)(xa.y & 0xffffu));
  float r3 = b2f((u16)(ya.y >> 16))   *wf.w + b2f((u16)(xa.y >> 16));
  uint2 o; o.x = (u32)f2b(r0) | ((u32)f2b(r1)<<16); o.y = (u32)f2b(r2) | ((u32)f2b(r3)<<16);
  *(uint2*)(x3 + e) = o;
}

// ---------------- fused [combine] + MLP with LN folded into W1 (MFMA, 64-tok, 4-phase hidQ) ----------------
__global__ __launch_bounds__(256, 2) void k_mlp(const u16* __restrict__ src0, const u16* __restrict__ src1,
    const float* __restrict__ wgt, int fused, const u16* __restrict__ W1pk,
    const float* __restrict__ w1gd, const float* __restrict__ wcv,
    const u16* __restrict__ W2pk, const float* __restrict__ mb2,
    float* __restrict__ out){
  __shared__ u16 lnS[64][200];         // raw combined x3 (NEVER overwritten)
  __shared__ u16 hidQ[64*192];         // quarter-hidden [tok][ho'], rows 384B, byte ^= ((tok&7)<<4)
  __shared__ float mu[64], rsg[64];
  int blk = blockIdx.x, t = threadIdx.x;
  int b = blk / 576; int rem = blk % 576;
  int h = rem / 3; int w0 = (rem % 3) * 64;
  size_t tokbase = ((size_t)b*192 + h)*192 + w0;
  int wid = t >> 6, l = t & 63, l15 = l & 15, lg = l >> 4;
  char* hb = (char*)hidQ;
  if (fused){
    for (int idx = t; idx < 1536; idx += 256){
      int tok = idx / 24, q = idx % 24;
      uint4 yv = *(const uint4*)(src0 + (tokbase + tok)*192 + q*8);
      uint4 xv = *(const uint4*)(src1 + (tokbase + tok)*192 + q*8);
      const float* wb = wgt + b*192 + q*8;
      uint4 res;
      u32* yp = (u32*)&yv; u32* xp = (u32*)&xv; u32* rp = (u32*)&res;
      #pragma unroll
      for (int w2 = 0; w2 < 4; ++w2){
        float r0 = b2f((u16)(yp[w2] & 0xffffu))*wb[2*w2]   + b2f((u16)(xp[w2] & 0xffffu));
        float r1 = b2f((u16)(yp[w2] >> 16))   *wb[2*w2+1] + b2f((u16)(xp[w2] >> 16));
        rp[w2] = cvtpk(r0, r1);
      }
      *(uint4*)&lnS[tok][q*8] = res;
    }
  } else {
    for (int idx = t; idx < 1536; idx += 256){
      int tok = idx / 24, q = idx % 24;
      *(uint4*)&lnS[tok][q*8] = *(const uint4*)(src0 + (tokbase + tok)*192 + q*8);
    }
  }
  __syncthreads();
  // stats: tok = t>>2, part = t&3; 48 ch per part (6 strided uint4), 4-lane shfl reduce
  { int tok = t >> 2, part = t & 3;
    float s = 0.f, s2 = 0.f;
    #pragma unroll
    for (int i = 0; i < 6; ++i){
      uint4 v = *(const uint4*)&lnS[tok][part*8 + 32*i];
      u32* vp = (u32*)&v;
      #pragma unroll
      for (int q = 0; q < 4; ++q){
        float a = b2f((u16)(vp[q] & 0xffffu)), c2 = b2f((u16)(vp[q] >> 16));
        s += a + c2; s2 += a*a + c2*c2;
      }
    }
    #pragma unroll
    for (int d = 1; d < 4; d <<= 1){
      s  += __shfl_xor(s, d);
      s2 += __shfl_xor(s2, d);
    }
    if (part == 0){
      float m = s*(1.f/192.f); float v = s2*(1.f/192.f) - m*m;
      mu[tok] = m; rsg[tok] = rsqrtf(v + 1e-5f);
    } }
  __syncthreads();
  // per-lane LN scalars (tok = tt*16 + l15 is lane-constant in swapped GEMM1)
  float rsgL[4], rmuL[4];
  #pragma unroll
  for (int tt = 0; tt < 4; ++tt){
    rsgL[tt] = rsg[tt*16 + l15];
    rmuL[tt] = rsgL[tt]*mu[tt*16 + l15];
  }
  int nb = wid*3;
  // four phases: GEMM1 quarter (ho' 192-wide) -> GEMM2 partial (kc 6); acc2 carried
  f32x4 acc2[4][3];
  #pragma unroll
  for (int mt = 0; mt < 4; ++mt)
    #pragma unroll
    for (int j = 0; j < 3; ++j) acc2[mt][j] = (f32x4){0.f,0.f,0.f,0.f};
  #pragma unroll
  for (int ph = 0; ph < 4; ++ph){
    // hoist W1 frags + dot-vectors for this phase's 3 ho-tiles (batch-issued L2 loads)
    bf16x8 aw[3][6];
    float4 gd[3], wc4[3];
    #pragma unroll
    for (int i = 0; i < 3; ++i){
      int hot = ph*12 + wid*3 + i;
      #pragma unroll
      for (int kc = 0; kc < 6; ++kc)
        aw[i][kc] = *(const bf16x8*)(W1pk + ((size_t)(hot*6 + kc)*64 + l)*8);
      gd[i]  = *(const float4*)(w1gd + hot*16 + lg*4);
      wc4[i] = *(const float4*)(wcv + hot*16 + lg*4);
    }
    // GEMM1: D[ho][tok] = W1g x x3^T; LN applied in epilogue
    #pragma unroll
    for (int tt = 0; tt < 4; ++tt){
      bf16x8 bT[6];
      #pragma unroll
      for (int kc = 0; kc < 6; ++kc)
        bT[kc] = *(const bf16x8*)&lnS[tt*16 + l15][kc*32 + lg*8];
      #pragma unroll
      for (int i = 0; i < 3; ++i){
        f32x4 acc = (f32x4){0.f,0.f,0.f,0.f};
        __builtin_amdgcn_s_setprio(1);
        #pragma unroll
        for (int kc = 0; kc < 6; ++kc)
          acc = mfma16(aw[i][kc], bT[kc], acc);
        __builtin_amdgcn_s_setprio(0);
        float h0 = fmaf(rsgL[tt], acc[0], fmaf(-rmuL[tt], gd[i].x, wc4[i].x));
        float h1 = fmaf(rsgL[tt], acc[1], fmaf(-rmuL[tt], gd[i].y, wc4[i].y));
        float h2 = fmaf(rsgL[tt], acc[2], fmaf(-rmuL[tt], gd[i].z, wc4[i].z));
        float h3 = fmaf(rsgL[tt], acc[3], fmaf(-rmuL[tt], gd[i].w, wc4[i].w));
        u32 p0 = cvtpk(gelu_f(h0), gelu_f(h1));
        u32 p1 = cvtpk(gelu_f(h2), gelu_f(h3));
        int tok = tt*16 + l15;
        int hoL = (wid*3 + i)*16 + lg*4;   // local ho' in [0,192)
        int byt = (tok*384 + hoL*2) ^ ((l15 & 7) << 4);
        *(uint2*)(hb + byt) = make_uint2(p0, p1);
      }
    }
    __syncthreads();
    // GEMM2 partial: local kc in [0,6), global k-chunk = ph*6 + kc
    #pragma unroll 2
    for (int kc = 0; kc < 6; ++kc){
      bf16x8 a[4];
      #pragma unroll
      for (int mt = 0; mt < 4; ++mt){
        int by = ((mt*16 + l15)*384 + (kc*32 + lg*8)*2) ^ ((l15 & 7) << 4);
        a[mt] = *(const bf16x8*)(hb + by);
      }
      bf16x8 bw3[3];
      #pragma unroll
      for (int j = 0; j < 3; ++j)
        bw3[j] = *(const bf16x8*)(W2pk + (((size_t)(nb + j)*24 + ph*6 + kc)*64 + l)*8);
      __builtin_amdgcn_s_setprio(1);
      #pragma unroll
      for (int j = 0; j < 3; ++j)
        #pragma unroll
        for (int mt = 0; mt < 4; ++mt)
          acc2[mt][j] = mfma16(a[mt], bw3[j], acc2[mt][j]);
      __builtin_amdgcn_s_setprio(0);
    }
    __syncthreads();
  }
  // epilogue: bias + residual (lnS intact), float4 stores to BCHW
  #pragma unroll
  for (int j = 0; j < 3; ++j){
    int co = (nb + j)*16 + l15;
    float bj = mb2[co];
    #pragma unroll
    for (int mt = 0; mt < 4; ++mt){
      int tok0 = mt*16 + lg*4;
      float4 ov;
      #pragma unroll
      for (int r = 0; r < 4; ++r)
        ((float*)&ov)[r] = b2f(lnS[tok0 + r][co]) + acc2[mt][j][r] + bj;
      *(float4*)(out + (((size_t)b*192 + co)*192 + h)*192 + w0 + tok0) = ov;
    }
  }
}

extern "C" void kernel_launch(void* const* d_in, const int* in_sizes, int n_in,
                              void* d_out, int out_size, void* d_ws, size_t ws_size,
                              hipStream_t stream){
  const float* x      = (const float*)d_in[0];
  const float* n1g    = (const float*)d_in[1];
  const float* n1b    = (const float*)d_in[2];
  const float* qkv_w  = (const float*)d_in[3];
  const float* qkv_b  = (const float*)d_in[4];
  const float* rel_t  = (const float*)d_in[5];
  const float* n2g    = (const float*)d_in[6];
  const float* n2b    = (const float*)d_in[7];
  const float* mlp_w1 = (const float*)d_in[8];
  const float* mlp_b1 = (const float*)d_in[9];
  const float* mlp_w2 = (const float*)d_in[10];
  const float* mlp_b2 = (const float*)d_in[11];
  const float* c1w    = (const float*)d_in[12];
  const float* c1b    = (const float*)d_in[13];
  const float* c2w    = (const float*)d_in[14];
  const float* c2b    = (const float*)d_in[15];
  const float* sew1   = (const float*)d_in[16];
  const float* seb1   = (const float*)d_in[17];
  const float* sew2   = (const float*)d_in[18];
  const float* seb2   = (const float*)d_in[19];
  const float* gw     = (const float*)d_in[20];
  const float* gb     = (const float*)d_in[21];

  const size_t E  = (size_t)4*192*192*192;
  const size_t EB = E*2;
  const size_t SMALL = 663552*2 + 221184 + 98304 + 294912*2 + 4*576*192*4 + 768*4*3 + 65536;
  char* ws = (char*)d_ws;
  u16* ws0 = (u16*)(ws);
  u16* ws1 = (u16*)(ws + EB);
  size_t off = 2*EB;
  int use_xn = (ws_size >= 3*EB + SMALL) ? 1 : 0;
  u16* xn = nullptr;
  if (use_xn){ xn = (u16*)(ws + off); off += EB; }
  u16* Wpk1  = (u16*)(ws + off); off += 663552;
  u16* Wpk2  = (u16*)(ws + off); off += 663552;
  u16* Qkvpk = (u16*)(ws + off); off += 221184;
  float* biasT = (float*)(ws + off); off += 98304;
  u16* W1pk = (u16*)(ws + off); off += 294912;
  u16* W2pk = (u16*)(ws + off); off += 294912;
  float* w1gd = (float*)(ws + off); off += 768*4;
  float* wcv  = (float*)(ws + off); off += 768*4;
  float* pp  = (float*)(ws + off); off += (size_t)4*576*192*4;
  float* wgt = (float*)(ws + off); off += 768*4;

  if (use_xn) k_transpose<<<6912, 256, 0, stream>>>(x, xn);
  k_prep_all<<<2979, 256, 0, stream>>>(c1w, c2w, qkv_w, rel_t, mlp_w1, mlp_w2,
                                       n2g, n2b, mlp_b1,
                                       Wpk1, Wpk2, Qkvpk, biasT, W1pk, W2pk, w1gd, wcv);

  k_attn<<<2304, 768, 0, stream>>>(x, xn, use_xn, n1g, n1b, Qkvpk, qkv_b, biasT, ws0);
  k_gate<<<18432, 192, 0, stream>>>(ws0, gw, gb, ws1);
  k_conv<<<2304, 256, 0, stream>>>(ws1, Wpk1, c1b, ws0, 1, nullptr);
  u16* y2 = use_xn ? xn : (u16*)d_out;
  k_conv<<<2304, 256, 0, stream>>>(ws0, Wpk2, c2b, y2, 0, pp);
  k_se<<<4, 256, 0, stream>>>(pp, sew1, seb1, sew2, seb2, wgt);
  if (use_xn){
    k_mlp<<<2304, 256, 0, stream>>>(y2, ws1, wgt, 1, W1pk, w1gd, wcv, W2pk, mlp_b2, (float*)d_out);
  } else {
    k_combine<<<27648, 256, 0, stream>>>((const u16*)d_out, ws1, wgt, ws0);
    k_mlp<<<2304, 256, 0, stream>>>(ws0, ws0, wgt, 0, W1pk, w1gd, wcv, W2pk, mlp_b2, (float*)d_out);
  }
}

// Round 17
// 570.350 us; speedup vs baseline: 1.0850x; 1.0166x over previous
//
#include <hip/hip_runtime.h>
#include <hip/hip_bf16.h>

#define NWIN 576
#define SP 36864
#define ATT_SCALE 0.17677669529663687f

typedef unsigned short u16;
typedef unsigned int u32;
typedef __attribute__((ext_vector_type(8))) __bf16 bf16x8;
typedef __attribute__((ext_vector_type(4))) float f32x4;

__device__ __forceinline__ float b2f(u16 u){ return __uint_as_float(((u32)u)<<16); }
__device__ __forceinline__ u16 f2b(float f){ u32 u = __float_as_uint(f); return (u16)((u + 0x7FFFu + ((u>>16)&1u)) >> 16); }
__device__ __forceinline__ float fast_rcp(float d){ float r; asm("v_rcp_f32 %0, %1" : "=v"(r) : "v"(d)); return r; }
__device__ __forceinline__ u32 cvtpk(float lo, float hi){ u32 r; asm("v_cvt_pk_bf16_f32 %0, %1, %2" : "=v"(r) : "v"(lo), "v"(hi)); return r; }
// tanh-form GELU: x*sigmoid(1.59577(x+0.044715x^3)); |err vs erf-GELU| <~1e-3
__device__ __forceinline__ float gelu_f(float v){
  float u = v*(1.5957691216f + 0.0713548163f*v*v);
  return v * fast_rcp(1.0f + __expf(-u));
}
__device__ __forceinline__ f32x4 mfma16(bf16x8 a, bf16x8 b, f32x4 c){
  return __builtin_amdgcn_mfma_f32_16x16x32_bf16(a, b, c, 0, 0, 0);
}

// ---------------- transpose BCHW fp32 -> NHWC bf16 (4 h-rows per block) ----------------
__global__ __launch_bounds__(256) void k_transpose(const float* __restrict__ x, u16* __restrict__ xn){
  __shared__ float tile[32][33];
  int blk = blockIdx.x;
  int b = blk / 1728; int rem = blk % 1728;
  int hg = rem / 36; int rem2 = rem % 36;
  int wt = rem2 / 6, ct = rem2 % 6;
  int t = threadIdx.x;
  int lw = t & 31, g = t >> 5;
  for (int r4 = 0; r4 < 4; ++r4){
    int h = hg*4 + r4;
    for (int r = 0; r < 4; ++r){
      int cl = g + r*8;
      tile[cl][lw] = x[(((size_t)b*192 + ct*32 + cl)*192 + h)*192 + wt*32 + lw];
    }
    __syncthreads();
    for (int r = 0; r < 4; ++r){
      int wl = g + r*8;
      xn[(((size_t)b*192 + h)*192 + wt*32 + wl)*192 + ct*32 + lw] = f2b(tile[lw][wl]);
    }
    __syncthreads();
  }
}

// ---------------- all weight prep in one kernel ----------------
__global__ __launch_bounds__(256) void k_prep_all(
    const float* __restrict__ c1w, const float* __restrict__ c2w,
    const float* __restrict__ qkv_w, const float* __restrict__ rel_table,
    const float* __restrict__ mlp_w1, const float* __restrict__ mlp_w2,
    const float* __restrict__ n2g, const float* __restrict__ n2b, const float* __restrict__ mb1,
    const float* __restrict__ n1g, const float* __restrict__ n1b, const float* __restrict__ qkv_b,
    u16* __restrict__ Wpk1, u16* __restrict__ Wpk2, u16* __restrict__ Qkvpk,
    float* __restrict__ biasT, u16* __restrict__ W1pk, u16* __restrict__ W2pk,
    float* __restrict__ w1gd, float* __restrict__ wcv,
    float* __restrict__ qgd, float* __restrict__ qwc){
  int i = blockIdx.x*256 + threadIdx.x;
  if (i < 331776){
    int j = i & 7; int l = (i >> 3) & 63; int rem = i >> 9;
    int nt = rem % 12; int rem2 = rem / 12; int kc = rem2 % 6; int tap = rem2 / 6;
    int ci = kc*32 + ((l>>4)<<3) + j;
    int co = nt*16 + (l & 15);
    Wpk1[i] = f2b(c1w[(co*192 + ci)*9 + tap]);
    Wpk2[i] = f2b(c2w[(co*192 + ci)*9 + tap]);
    return;
  }
  i -= 331776;
  if (i < 110592){
    // qkv weights pre-scaled by norm1 gamma (LN1 fold)
    int j = i & 7; int l = (i >> 3) & 63; int rem = i >> 9;
    int kc = rem % 6; int nt = rem / 6;
    int row = nt*16 + (l & 15); int c = kc*32 + ((l>>4)<<3) + j;
    Qkvpk[i] = f2b(qkv_w[row*192 + c] * n1g[c]);
    return;
  }
  i -= 110592;
  if (i < 24576){
    // biasT[h][k][q]
    int q = i & 63; int k = (i>>6) & 63; int h = i >> 12;
    int di = (q>>3) - (k>>3) + 7; int dj = (q&7) - (k&7) + 7;
    biasT[i] = rel_table[(di*15 + dj)*6 + h];
    return;
  }
  i -= 24576;
  if (i < 147456){
    // W1 pre-scaled by norm2 gamma (LN fold)
    int j = i & 7; int l = (i >> 3) & 63; int rem = i >> 9;
    int kc = rem % 6; int nt = rem / 6;
    int ho = nt*16 + (l & 15); int ci = kc*32 + ((l>>4)<<3) + j;
    W1pk[i] = f2b(mlp_w1[ho*192 + ci] * n2g[ci]);
    return;
  }
  i -= 147456;
  if (i < 147456){
    int j = i & 7; int l = (i >> 3) & 63; int rem = i >> 9;
    int kc = rem % 24; int nt = rem / 24;
    int co = nt*16 + (l & 15); int ho = kc*32 + ((l>>4)<<3) + j;
    W2pk[i] = f2b(mlp_w2[co*768 + ho]);
    return;
  }
  i -= 147456;
  if (i < 768){
    // dot-vectors for mlp LN fold: w1gd = W1·g ; wcv = W1·b + mb1
    float sg = 0.f, sb = 0.f;
    const float* row = mlp_w1 + (size_t)i*192;
    for (int ci = 0; ci < 192; ++ci){ float w = row[ci]; sg += w*n2g[ci]; sb += w*n2b[ci]; }
    w1gd[i] = sg; wcv[i] = sb + mb1[i];
    return;
  }
  i -= 768;
  if (i < 576){
    // dot-vectors for qkv LN1 fold: qgd = Wq·g1 ; qwc = Wq·b1 + qkv_b
    float sg = 0.f, sb = 0.f;
    const float* row = qkv_w + (size_t)i*192;
    for (int c = 0; c < 192; ++c){ float w = row[c]; sg += w*n1g[c]; sb += w*n1b[c]; }
    qgd[i] = sg; qwc[i] = sb + qkv_b[i];
  }
}

// ---------------- fused shifted-window attention, LN1 folded into qkv weights ----------------
__global__ __launch_bounds__(768, 3) void k_attn(const float* __restrict__ x, const u16* __restrict__ xn, int use_xn,
    const u16* __restrict__ qkvpk, const float* __restrict__ qgd, const float* __restrict__ qwc,
    const float* __restrict__ biasT, u16* __restrict__ x1)
{
  __shared__ u16 xw[12800];            // [64][200]: RAW input -> (after qkv) O staging
  __shared__ u16 qs[6][64][40];
  __shared__ u16 ks[6][64][40];
  __shared__ u16 vt[6][32][72];
  __shared__ int ih[64], iw[64], rid[64];
  __shared__ float2 musig[64];         // (rsg, -rsg*mu)
  int blk = blockIdx.x, t = threadIdx.x;
  int b = blk / NWIN, wi = blk % NWIN, wy = wi / 24, wx = wi % 24;
  int wid = t >> 6, l = t & 63, l15 = l & 15, lg = l >> 4;
  if (t < 64){
    int i = t >> 3, j = t & 7;
    int gh = wy*8 + i, gw = wx*8 + j;
    int hf = gh + 4; if (hf >= 192) hf -= 192;
    int wf = gw + 4; if (wf >= 192) wf -= 192;
    ih[t] = hf; iw[t] = wf;
    int rh = (gh < 184) ? 0 : ((gh < 188) ? 1 : 2);
    int rw = (gw < 184) ? 0 : ((gw < 188) ? 1 : 2);
    rid[t] = rh*3 + rw;
  }
  __syncthreads();
  // ---- load RAW tokens ----
  if (use_xn){
    for (int idx = t; idx < 1536; idx += 768){
      int n = idx / 24, q = idx % 24;
      *(uint4*)&xw[n*200 + q*8] =
        *(const uint4*)(xn + ((size_t)((b*192 + ih[n])*192 + iw[n]))*192 + q*8);
    }
  } else {
    for (int idx = t; idx < 12288; idx += 768){
      int n = idx & 63, c = idx >> 6;
      xw[n*200 + c] = f2b(x[(((size_t)b*192 + c)*192 + ih[n])*192 + iw[n]]);
    }
  }
  __syncthreads();
  // ---- LN stats only (no transform): 64 toks x 8 parts x 24ch, 8-lane shfl reduce ----
  if (t < 512){
    int tok = t >> 3, part = t & 7;
    float s = 0.f, s2 = 0.f;
    #pragma unroll
    for (int i = 0; i < 3; ++i){
      uint4 v = *(const uint4*)&xw[tok*200 + part*8 + 64*i];
      u32* vp = (u32*)&v;
      #pragma unroll
      for (int q = 0; q < 4; ++q){
        float a = b2f((u16)(vp[q] & 0xffffu)), c2 = b2f((u16)(vp[q] >> 16));
        s += a + c2; s2 += a*a + c2*c2;
      }
    }
    #pragma unroll
    for (int d = 1; d < 8; d <<= 1){
      s  += __shfl_xor(s, d);
      s2 += __shfl_xor(s2, d);
    }
    if (part == 0){
      float m = s*(1.f/192.f); float v = s2*(1.f/192.f) - m*m;
      float rs = rsqrtf(v + 1e-5f);
      musig[tok] = make_float2(rs, -rs*m);
    }
  }
  __syncthreads();
  // ---- qkv GEMM on RAW x; LN applied in epilogue via per-token (rsg, -rsg*mu) ----
  {
    f32x4 acc[3][4];
    #pragma unroll
    for (int i3 = 0; i3 < 3; ++i3)
      #pragma unroll
      for (int mt = 0; mt < 4; ++mt) acc[i3][mt] = (f32x4){0.f,0.f,0.f,0.f};
    #pragma unroll
    for (int kc = 0; kc < 6; ++kc){
      bf16x8 a4[4];
      #pragma unroll
      for (int mt = 0; mt < 4; ++mt)
        a4[mt] = *(const bf16x8*)&xw[(mt*16 + l15)*200 + kc*32 + lg*8];
      #pragma unroll
      for (int i3 = 0; i3 < 3; ++i3){
        int ntg = wid*3 + i3;
        bf16x8 bf = *(const bf16x8*)(qkvpk + ((size_t)ntg*6 + kc)*512 + l*8);
        #pragma unroll
        for (int mt = 0; mt < 4; ++mt)
          acc[i3][mt] = mfma16(a4[mt], bf, acc[i3][mt]);
      }
    }
    float2 msr[4][4];
    #pragma unroll
    for (int mt = 0; mt < 4; ++mt)
      #pragma unroll
      for (int r = 0; r < 4; ++r)
        msr[mt][r] = musig[mt*16 + lg*4 + r];
    #pragma unroll
    for (int i3 = 0; i3 < 3; ++i3){
      int ntg = wid*3 + i3;
      int rowg = ntg*16 + l15;
      float gd = qgd[rowg];
      float wc = qwc[rowg];
      int m = ntg/12, hh = (ntg%12)>>1, hd0 = (ntg&1)*16;
      #pragma unroll
      for (int mt = 0; mt < 4; ++mt)
        #pragma unroll
        for (int r = 0; r < 4; ++r){
          int tok = mt*16 + lg*4 + r;
          float2 ms = msr[mt][r];
          float val = fmaf(ms.x, acc[i3][mt][r], fmaf(ms.y, gd, wc));
          if (m == 0){ qs[hh][tok][hd0 + l15] = f2b(val * ATT_SCALE); }
          else if (m == 1){ ks[hh][tok][hd0 + l15] = f2b(val); }
          else { vt[hh][hd0 + l15][tok] = f2b(val); }
        }
    }
  }
  __syncthreads();
  // ---- attention: wave = (head h, q-half mt0) ----
  int h = wid >> 1, mt0 = (wid & 1) * 2;
  // swapped QK^T: S^T frags, lane holds q = l15, k = nt*16 + lg*4 + r
  f32x4 st[2][4];
  {
    bf16x8 bq0 = *(const bf16x8*)&qs[h][(mt0  )*16 + l15][lg*8];
    bf16x8 bq1 = *(const bf16x8*)&qs[h][(mt0+1)*16 + l15][lg*8];
    #pragma unroll
    for (int nt = 0; nt < 4; ++nt){
      bf16x8 ak = *(const bf16x8*)&ks[h][nt*16 + l15][lg*8];
      st[0][nt] = mfma16(ak, bq0, (f32x4){0.f,0.f,0.f,0.f});
      st[1][nt] = mfma16(ak, bq1, (f32x4){0.f,0.f,0.f,0.f});
    }
  }
  // bias + mask + in-register softmax + pack to bf16 pairs
  u32 pk[2][4][2];
  #pragma unroll
  for (int m2 = 0; m2 < 2; ++m2){
    int qg = (mt0 + m2)*16 + l15;
    int rq = rid[qg];
    const float* bp = biasT + (size_t)h*4096 + qg;
    float mx = -1e30f;
    #pragma unroll
    for (int nt = 0; nt < 4; ++nt)
      #pragma unroll
      for (int r = 0; r < 4; ++r){
        int kg = nt*16 + lg*4 + r;
        float v = st[m2][nt][r] + bp[kg*64] + (rq != rid[kg] ? -100.f : 0.f);
        st[m2][nt][r] = v;
        mx = fmaxf(mx, v);
      }
    mx = fmaxf(mx, __shfl_xor(mx, 16));
    mx = fmaxf(mx, __shfl_xor(mx, 32));
    float ssum = 0.f;
    #pragma unroll
    for (int nt = 0; nt < 4; ++nt)
      #pragma unroll
      for (int r = 0; r < 4; ++r){
        float e = __expf(st[m2][nt][r] - mx);
        st[m2][nt][r] = e; ssum += e;
      }
    ssum += __shfl_xor(ssum, 16);
    ssum += __shfl_xor(ssum, 32);
    float inv = fast_rcp(ssum);
    #pragma unroll
    for (int nt = 0; nt < 4; ++nt){
      pk[m2][nt][0] = cvtpk(st[m2][nt][0]*inv, st[m2][nt][1]*inv);
      pk[m2][nt][1] = cvtpk(st[m2][nt][2]*inv, st[m2][nt][3]*inv);
    }
  }
  // PV: repack P via shfl into A-frags; B = V rows
  f32x4 o[2][2];
  #pragma unroll
  for (int m2 = 0; m2 < 2; ++m2)
    #pragma unroll
    for (int nd = 0; nd < 2; ++nd) o[m2][nd] = (f32x4){0.f,0.f,0.f,0.f};
  {
    int srcA = ((lg & 1) << 1)*16 + l15;
    bool hiSel = (lg & 2) != 0;
    #pragma unroll
    for (int kc = 0; kc < 2; ++kc){
      bf16x8 bv0 = *(const bf16x8*)&vt[h][l15][kc*32 + lg*8];
      bf16x8 bv1 = *(const bf16x8*)&vt[h][16 + l15][kc*32 + lg*8];
      #pragma unroll
      for (int m2 = 0; m2 < 2; ++m2){
        u32 q0 = __shfl((int)pk[m2][2*kc  ][0], srcA);
        u32 q1 = __shfl((int)pk[m2][2*kc+1][0], srcA);
        u32 q2 = __shfl((int)pk[m2][2*kc  ][1], srcA);
        u32 q3 = __shfl((int)pk[m2][2*kc+1][1], srcA);
        u32 q4 = __shfl((int)pk[m2][2*kc  ][0], srcA + 16);
        u32 q5 = __shfl((int)pk[m2][2*kc+1][0], srcA + 16);
        u32 q6 = __shfl((int)pk[m2][2*kc  ][1], srcA + 16);
        u32 q7 = __shfl((int)pk[m2][2*kc+1][1], srcA + 16);
        union { u32 u[4]; bf16x8 v; } ap;
        ap.u[0] = hiSel ? q1 : q0;
        ap.u[1] = hiSel ? q3 : q2;
        ap.u[2] = hiSel ? q5 : q4;
        ap.u[3] = hiSel ? q7 : q6;
        o[m2][0] = mfma16(ap.v, bv0, o[m2][0]);
        o[m2][1] = mfma16(ap.v, bv1, o[m2][1]);
      }
    }
  }
  // stage O into xw (input region dead after qkv barrier)
  #pragma unroll
  for (int m2 = 0; m2 < 2; ++m2)
    #pragma unroll
    for (int nd = 0; nd < 2; ++nd)
      #pragma unroll
      for (int r = 0; r < 4; ++r){
        int tok = (mt0 + m2)*16 + lg*4 + r;
        xw[tok*200 + h*32 + nd*16 + l15] = f2b(o[m2][nd][r]);
      }
  __syncthreads();
  // ---- residual add + store NHWC bf16 ----
  if (use_xn){
    for (int idx = t; idx < 1536; idx += 768){
      int n = idx / 24, q = idx % 24;
      size_t tokoff = (size_t)((b*192 + ih[n])*192 + iw[n]);
      uint4 xv = *(const uint4*)(xn + tokoff*192 + q*8);
      uint4 ov = *(const uint4*)&xw[n*200 + q*8];
      uint4 res;
      u32* xp = (u32*)&xv; u32* op = (u32*)&ov; u32* rp = (u32*)&res;
      #pragma unroll
      for (int w2 = 0; w2 < 4; ++w2){
        float a0 = b2f((u16)(xp[w2] & 0xffffu)) + b2f((u16)(op[w2] & 0xffffu));
        float a1 = b2f((u16)(xp[w2] >> 16))    + b2f((u16)(op[w2] >> 16));
        rp[w2] = (u32)f2b(a0) | ((u32)f2b(a1) << 16);
      }
      *(uint4*)(x1 + tokoff*192 + q*8) = res;
    }
  } else {
    for (int idx = t; idx < 12288; idx += 768){
      int n = idx & 63, c = idx >> 6;
      size_t tokoff = (size_t)((b*192 + ih[n])*192 + iw[n]);
      float sc = x[(((size_t)b*192 + c)*192 + ih[n])*192 + iw[n]];
      x1[tokoff*192 + c] = f2b(sc + b2f(xw[n*200 + c]));
    }
  }
}

// ---------------- depthwise 3x3 gate: x2 = x1 + dw(x1), 8-w tiles, XCD-swizzled ----------------
__global__ __launch_bounds__(192) void k_gate(const u16* __restrict__ x1, const float* __restrict__ gw,
                                              const float* __restrict__ gb, u16* __restrict__ x2){
  int bid = blockIdx.x;
  int blk = (bid & 7) * 2304 + (bid >> 3);   // 18432 = 8*2304: each XCD gets contiguous h-range
  int wt = blk % 24; int rem = blk / 24;
  int h = rem % 192; int b = rem / 192;
  int c = threadIdx.x;
  int w0 = wt*8;
  float wr[9];
  #pragma unroll
  for (int p = 0; p < 9; ++p) wr[p] = gw[c*9 + p];
  float bias = gb[c];
  float in[3][10];
  #pragma unroll
  for (int dy = 0; dy < 3; ++dy){
    int hh = h + dy - 1;
    bool hok = (hh >= 0 && hh < 192);
    #pragma unroll
    for (int p = 0; p < 10; ++p){
      int ww = w0 + p - 1;
      bool ok = hok && (ww >= 0 && ww < 192);
      in[dy][p] = ok ? b2f(x1[(((size_t)b*192 + hh)*192 + ww)*192 + c]) : 0.f;
    }
  }
  size_t rowbase = ((size_t)b*192 + h)*192;
  #pragma unroll
  for (int i = 0; i < 8; ++i){
    float acc = bias;
    #pragma unroll
    for (int dy = 0; dy < 3; ++dy)
      #pragma unroll
      for (int dx = 0; dx < 3; ++dx)
        acc += in[dy][i + dx] * wr[dy*3 + dx];
    float v = in[1][i + 1] + acc;
    x2[(rowbase + w0 + i)*192 + c] = f2b(v);
  }
}

// ---------------- 3x3 full conv, NHWC, MFMA implicit GEMM, XCD-swizzled, optional fused pool ----------------
__global__ __launch_bounds__(256) void k_conv(const u16* __restrict__ src, const u16* __restrict__ wpk,
                                              const float* __restrict__ cb, u16* __restrict__ dst,
                                              int do_gelu, float* __restrict__ pp){
  __shared__ u16 tin[20592];   // [3][66][104] ci-half tile; reused as obuf[64][200]
  int bid = blockIdx.x;
  int blk = (bid & 7) * 288 + (bid >> 3);    // 2304 = 8*288: each XCD gets contiguous h-range (halo L2-hits)
  int b = blk / 576; int rem = blk % 576;
  int h = rem / 3; int w0 = (rem % 3) * 64;
  int t = threadIdx.x;
  int wid = t >> 6, l = t & 63;
  int l15 = l & 15, lg = l >> 4;
  f32x4 acc[4][3];
  #pragma unroll
  for (int mt = 0; mt < 4; ++mt)
    #pragma unroll
    for (int j = 0; j < 3; ++j) acc[mt][j] = (f32x4){0.f,0.f,0.f,0.f};
  for (int ch = 0; ch < 2; ++ch){
    __syncthreads();
    for (int idx = t; idx < 2376; idx += 256){
      int r = idx / 792; int r2 = idx % 792; int p = r2 / 12; int q = r2 % 12;
      int hh = h + r - 1, ww = w0 + p - 1;
      uint4 v = make_uint4(0u,0u,0u,0u);
      if (hh >= 0 && hh < 192 && ww >= 0 && ww < 192)
        v = *(const uint4*)(src + (((size_t)(b*192 + hh))*192 + ww)*192 + ch*96 + q*8);
      *(uint4*)&tin[(r*66 + p)*104 + q*8] = v;
    }
    __syncthreads();
    for (int dy = 0; dy < 3; ++dy){
      for (int kch = 0; kch < 3; ++kch){
        bf16x8 af[4][3];
        #pragma unroll
        for (int mt = 0; mt < 4; ++mt)
          #pragma unroll
          for (int dx = 0; dx < 3; ++dx)
            af[mt][dx] = *(const bf16x8*)&tin[(dy*66 + mt*16 + l15 + dx)*104 + kch*32 + lg*8];
        bf16x8 bw[3][3];
        int kc = ch*3 + kch;
        #pragma unroll
        for (int dx = 0; dx < 3; ++dx)
          #pragma unroll
          for (int j = 0; j < 3; ++j)
            bw[dx][j] = *(const bf16x8*)(wpk + ((((size_t)(dy*3+dx)*6 + kc)*12 + wid*3 + j)*64 + l)*8);
        __builtin_amdgcn_s_setprio(1);
        #pragma unroll
        for (int dx = 0; dx < 3; ++dx)
          #pragma unroll
          for (int j = 0; j < 3; ++j)
            #pragma unroll
            for (int mt = 0; mt < 4; ++mt)
              acc[mt][j] = mfma16(af[mt][dx], bw[dx][j], acc[mt][j]);
        __builtin_amdgcn_s_setprio(0);
      }
    }
  }
  __syncthreads();
  float bv[3];
  #pragma unroll
  for (int j = 0; j < 3; ++j) bv[j] = cb[wid*48 + j*16 + l15];
  #pragma unroll
  for (int mt = 0; mt < 4; ++mt)
    #pragma unroll
    for (int j = 0; j < 3; ++j)
      #pragma unroll
      for (int r = 0; r < 4; ++r){
        int pix = mt*16 + lg*4 + r;
        float v = acc[mt][j][r] + bv[j];
        if (do_gelu) v = gelu_f(v);
        tin[pix*200 + wid*48 + j*16 + l15] = f2b(v);
      }
  __syncthreads();
  for (int idx = t; idx < 1536; idx += 256){
    int pix = idx / 24, q = idx % 24;
    *(uint4*)(dst + (((size_t)(b*192 + h))*192 + w0 + pix)*192 + q*8) = *(const uint4*)&tin[pix*200 + q*8];
  }
  if (pp){
    // fused pool partial: sum over this block's 64 pixels per channel
    if (t < 192){
      float s = 0.f;
      #pragma unroll 8
      for (int pix = 0; pix < 64; ++pix) s += b2f(tin[pix*200 + t]);
      pp[(size_t)blk*192 + t] = s;
    }
  }
}

// ---------------- SE MLP (one block per batch; reduces 576 conv-block partials) ----------------
__global__ __launch_bounds__(256) void k_se(const float* __restrict__ pp, const float* __restrict__ w1,
    const float* __restrict__ bb1, const float* __restrict__ w2, const float* __restrict__ bb2,
    float* __restrict__ wgt){
  __shared__ float pb[192]; __shared__ float hq[12];
  int t = threadIdx.x;
  int b = blockIdx.x;
  if (t < 192){
    float s = 0.f;
    const float* base = pp + (size_t)b*576*192 + t;
    for (int ch = 0; ch < 576; ++ch) s += base[ch*192];
    pb[t] = s * (1.f/36864.f);
  }
  __syncthreads();
  if (t < 12){ float a = bb1[t]; for (int c = 0; c < 192; ++c) a += pb[c]*w1[t*192 + c]; hq[t] = fmaxf(a, 0.f); }
  __syncthreads();
  if (t < 192){ float a = bb2[t]; for (int m = 0; m < 12; ++m) a += hq[m]*w2[t*12 + m]; wgt[b*192 + t] = 1.f/(1.f + __expf(-a)); }
}

// ---------------- x3 = y2*wgt + x2 (fallback path only) ----------------
__global__ __launch_bounds__(256) void k_combine(const u16* __restrict__ y2, const u16* __restrict__ x2,
                                                 const float* __restrict__ wgt, u16* __restrict__ x3){
  size_t e = ((size_t)blockIdx.x*256 + threadIdx.x)*4;
  int c = (int)(e % 192);
  int b = (int)(e / ((size_t)SP*192));
  uint2 ya = *(const uint2*)(y2 + e);
  uint2 xa = *(const uint2*)(x2 + e);
  float4 wf = *(const float4*)(wgt + b*192 + c);
  float r0 = b2f((u16)(ya.x & 0xffffu))*wf.x + b2f((u16)(xa.x & 0xffffu));
  float r1 = b2f((u16)(ya.x >> 16))   *wf.y + b2f((u16)(xa.x >> 16));
  float r2 = b2f((u16)(ya.y & 0xffffu))*wf.z + b2f((u16)(xa.y & 0xffffu));
  float r3 = b2f((u16)(ya.y >> 16))   *wf.w + b2f((u16)(xa.y >> 16));
  uint2 o; o.x = (u32)f2b(r0) | ((u32)f2b(r1)<<16); o.y = (u32)f2b(r2) | ((u32)f2b(r3)<<16);
  *(uint2*)(x3 + e) = o;
}

// ---------------- fused [combine] + MLP with LN folded into W1 (MFMA, 64-tok, 4-phase hidQ) ----------------
__global__ __launch_bounds__(256, 2) void k_mlp(const u16* __restrict__ src0, const u16* __restrict__ src1,
    const float* __restrict__ wgt, int fused, const u16* __restrict__ W1pk,
    const float* __restrict__ w1gd, const float* __restrict__ wcv,
    const u16* __restrict__ W2pk, const float* __restrict__ mb2,
    float* __restrict__ out){
  __shared__ u16 lnS[64][200];         // raw combined x3 (NEVER overwritten)
  __shared__ u16 hidQ[64*192];         // quarter-hidden [tok][ho'], rows 384B, byte ^= ((tok&7)<<4)
  __shared__ float mu[64], rsg[64];
  int blk = blockIdx.x, t = threadIdx.x;
  int b = blk / 576; int rem = blk % 576;
  int h = rem / 3; int w0 = (rem % 3) * 64;
  size_t tokbase = ((size_t)b*192 + h)*192 + w0;
  int wid = t >> 6, l = t & 63, l15 = l & 15, lg = l >> 4;
  char* hb = (char*)hidQ;
  if (fused){
    for (int idx = t; idx < 1536; idx += 256){
      int tok = idx / 24, q = idx % 24;
      uint4 yv = *(const uint4*)(src0 + (tokbase + tok)*192 + q*8);
      uint4 xv = *(const uint4*)(src1 + (tokbase + tok)*192 + q*8);
      const float* wb = wgt + b*192 + q*8;
      uint4 res;
      u32* yp = (u32*)&yv; u32* xp = (u32*)&xv; u32* rp = (u32*)&res;
      #pragma unroll
      for (int w2 = 0; w2 < 4; ++w2){
        float r0 = b2f((u16)(yp[w2] & 0xffffu))*wb[2*w2]   + b2f((u16)(xp[w2] & 0xffffu));
        float r1 = b2f((u16)(yp[w2] >> 16))   *wb[2*w2+1] + b2f((u16)(xp[w2] >> 16));
        rp[w2] = cvtpk(r0, r1);
      }
      *(uint4*)&lnS[tok][q*8] = res;
    }
  } else {
    for (int idx = t; idx < 1536; idx += 256){
      int tok = idx / 24, q = idx % 24;
      *(uint4*)&lnS[tok][q*8] = *(const uint4*)(src0 + (tokbase + tok)*192 + q*8);
    }
  }
  __syncthreads();
  // stats: tok = t>>2, part = t&3; 48 ch per part (6 strided uint4), 4-lane shfl reduce
  { int tok = t >> 2, part = t & 3;
    float s = 0.f, s2 = 0.f;
    #pragma unroll
    for (int i = 0; i < 6; ++i){
      uint4 v = *(const uint4*)&lnS[tok][part*8 + 32*i];
      u32* vp = (u32*)&v;
      #pragma unroll
      for (int q = 0; q < 4; ++q){
        float a = b2f((u16)(vp[q] & 0xffffu)), c2 = b2f((u16)(vp[q] >> 16));
        s += a + c2; s2 += a*a + c2*c2;
      }
    }
    #pragma unroll
    for (int d = 1; d < 4; d <<= 1){
      s  += __shfl_xor(s, d);
      s2 += __shfl_xor(s2, d);
    }
    if (part == 0){
      float m = s*(1.f/192.f); float v = s2*(1.f/192.f) - m*m;
      mu[tok] = m; rsg[tok] = rsqrtf(v + 1e-5f);
    } }
  __syncthreads();
  // per-lane LN scalars (tok = tt*16 + l15 is lane-constant in swapped GEMM1)
  float rsgL[4], rmuL[4];
  #pragma unroll
  for (int tt = 0; tt < 4; ++tt){
    rsgL[tt] = rsg[tt*16 + l15];
    rmuL[tt] = rsgL[tt]*mu[tt*16 + l15];
  }
  int nb = wid*3;
  // four phases: GEMM1 quarter (ho' 192-wide) -> GEMM2 partial (kc 6); acc2 carried
  f32x4 acc2[4][3];
  #pragma unroll
  for (int mt = 0; mt < 4; ++mt)
    #pragma unroll
    for (int j = 0; j < 3; ++j) acc2[mt][j] = (f32x4){0.f,0.f,0.f,0.f};
  #pragma unroll
  for (int ph = 0; ph < 4; ++ph){
    // hoist W1 frags + dot-vectors for this phase's 3 ho-tiles (batch-issued L2 loads)
    bf16x8 aw[3][6];
    float4 gd[3], wc4[3];
    #pragma unroll
    for (int i = 0; i < 3; ++i){
      int hot = ph*12 + wid*3 + i;
      #pragma unroll
      for (int kc = 0; kc < 6; ++kc)
        aw[i][kc] = *(const bf16x8*)(W1pk + ((size_t)(hot*6 + kc)*64 + l)*8);
      gd[i]  = *(const float4*)(w1gd + hot*16 + lg*4);
      wc4[i] = *(const float4*)(wcv + hot*16 + lg*4);
    }
    // GEMM1: D[ho][tok] = W1g x x3^T; LN applied in epilogue
    #pragma unroll
    for (int tt = 0; tt < 4; ++tt){
      bf16x8 bT[6];
      #pragma unroll
      for (int kc = 0; kc < 6; ++kc)
        bT[kc] = *(const bf16x8*)&lnS[tt*16 + l15][kc*32 + lg*8];
      #pragma unroll
      for (int i = 0; i < 3; ++i){
        f32x4 acc = (f32x4){0.f,0.f,0.f,0.f};
        __builtin_amdgcn_s_setprio(1);
        #pragma unroll
        for (int kc = 0; kc < 6; ++kc)
          acc = mfma16(aw[i][kc], bT[kc], acc);
        __builtin_amdgcn_s_setprio(0);
        float h0 = fmaf(rsgL[tt], acc[0], fmaf(-rmuL[tt], gd[i].x, wc4[i].x));
        float h1 = fmaf(rsgL[tt], acc[1], fmaf(-rmuL[tt], gd[i].y, wc4[i].y));
        float h2 = fmaf(rsgL[tt], acc[2], fmaf(-rmuL[tt], gd[i].z, wc4[i].z));
        float h3 = fmaf(rsgL[tt], acc[3], fmaf(-rmuL[tt], gd[i].w, wc4[i].w));
        u32 p0 = cvtpk(gelu_f(h0), gelu_f(h1));
        u32 p1 = cvtpk(gelu_f(h2), gelu_f(h3));
        int tok = tt*16 + l15;
        int hoL = (wid*3 + i)*16 + lg*4;   // local ho' in [0,192)
        int byt = (tok*384 + hoL*2) ^ ((l15 & 7) << 4);
        *(uint2*)(hb + byt) = make_uint2(p0, p1);
      }
    }
    __syncthreads();
    // GEMM2 partial: local kc in [0,6), global k-chunk = ph*6 + kc
    #pragma unroll 2
    for (int kc = 0; kc < 6; ++kc){
      bf16x8 a[4];
      #pragma unroll
      for (int mt = 0; mt < 4; ++mt){
        int by = ((mt*16 + l15)*384 + (kc*32 + lg*8)*2) ^ ((l15 & 7) << 4);
        a[mt] = *(const bf16x8*)(hb + by);
      }
      bf16x8 bw3[3];
      #pragma unroll
      for (int j = 0; j < 3; ++j)
        bw3[j] = *(const bf16x8*)(W2pk + (((size_t)(nb + j)*24 + ph*6 + kc)*64 + l)*8);
      __builtin_amdgcn_s_setprio(1);
      #pragma unroll
      for (int j = 0; j < 3; ++j)
        #pragma unroll
        for (int mt = 0; mt < 4; ++mt)
          acc2[mt][j] = mfma16(a[mt], bw3[j], acc2[mt][j]);
      __builtin_amdgcn_s_setprio(0);
    }
    __syncthreads();
  }
  // epilogue: bias + residual (lnS intact), float4 stores to BCHW
  #pragma unroll
  for (int j = 0; j < 3; ++j){
    int co = (nb + j)*16 + l15;
    float bj = mb2[co];
    #pragma unroll
    for (int mt = 0; mt < 4; ++mt){
      int tok0 = mt*16 + lg*4;
      float4 ov;
      #pragma unroll
      for (int r = 0; r < 4; ++r)
        ((float*)&ov)[r] = b2f(lnS[tok0 + r][co]) + acc2[mt][j][r] + bj;
      *(float4*)(out + (((size_t)b*192 + co)*192 + h)*192 + w0 + tok0) = ov;
    }
  }
}

extern "C" void kernel_launch(void* const* d_in, const int* in_sizes, int n_in,
                              void* d_out, int out_size, void* d_ws, size_t ws_size,
                              hipStream_t stream){
  const float* x      = (const float*)d_in[0];
  const float* n1g    = (const float*)d_in[1];
  const float* n1b    = (const float*)d_in[2];
  const float* qkv_w  = (const float*)d_in[3];
  const float* qkv_b  = (const float*)d_in[4];
  const float* rel_t  = (const float*)d_in[5];
  const float* n2g    = (const float*)d_in[6];
  const float* n2b    = (const float*)d_in[7];
  const float* mlp_w1 = (const float*)d_in[8];
  const float* mlp_b1 = (const float*)d_in[9];
  const float* mlp_w2 = (const float*)d_in[10];
  const float* mlp_b2 = (const float*)d_in[11];
  const float* c1w    = (const float*)d_in[12];
  const float* c1b    = (const float*)d_in[13];
  const float* c2w    = (const float*)d_in[14];
  const float* c2b    = (const float*)d_in[15];
  const float* sew1   = (const float*)d_in[16];
  const float* seb1   = (const float*)d_in[17];
  const float* sew2   = (const float*)d_in[18];
  const float* seb2   = (const float*)d_in[19];
  const float* gw     = (const float*)d_in[20];
  const float* gb     = (const float*)d_in[21];

  const size_t E  = (size_t)4*192*192*192;
  const size_t EB = E*2;
  const size_t SMALL = 663552*2 + 221184 + 98304 + 294912*2 + 4*576*192*4 + 768*4*3 + 576*4*2 + 65536;
  char* ws = (char*)d_ws;
  u16* ws0 = (u16*)(ws);
  u16* ws1 = (u16*)(ws + EB);
  size_t off = 2*EB;
  int use_xn = (ws_size >= 3*EB + SMALL) ? 1 : 0;
  u16* xn = nullptr;
  if (use_xn){ xn = (u16*)(ws + off); off += EB; }
  u16* Wpk1  = (u16*)(ws + off); off += 663552;
  u16* Wpk2  = (u16*)(ws + off); off += 663552;
  u16* Qkvpk = (u16*)(ws + off); off += 221184;
  float* biasT = (float*)(ws + off); off += 98304;
  u16* W1pk = (u16*)(ws + off); off += 294912;
  u16* W2pk = (u16*)(ws + off); off += 294912;
  float* w1gd = (float*)(ws + off); off += 768*4;
  float* wcv  = (float*)(ws + off); off += 768*4;
  float* qgd  = (float*)(ws + off); off += 576*4;
  float* qwc  = (float*)(ws + off); off += 576*4;
  float* pp  = (float*)(ws + off); off += (size_t)4*576*192*4;
  float* wgt = (float*)(ws + off); off += 768*4;

  if (use_xn) k_transpose<<<6912, 256, 0, stream>>>(x, xn);
  k_prep_all<<<2982, 256, 0, stream>>>(c1w, c2w, qkv_w, rel_t, mlp_w1, mlp_w2,
                                       n2g, n2b, mlp_b1, n1g, n1b, qkv_b,
                                       Wpk1, Wpk2, Qkvpk, biasT, W1pk, W2pk, w1gd, wcv, qgd, qwc);

  k_attn<<<2304, 768, 0, stream>>>(x, xn, use_xn, Qkvpk, qgd, qwc, biasT, ws0);
  k_gate<<<18432, 192, 0, stream>>>(ws0, gw, gb, ws1);
  k_conv<<<2304, 256, 0, stream>>>(ws1, Wpk1, c1b, ws0, 1, nullptr);
  u16* y2 = use_xn ? xn : (u16*)d_out;
  k_conv<<<2304, 256, 0, stream>>>(ws0, Wpk2, c2b, y2, 0, pp);
  k_se<<<4, 256, 0, stream>>>(pp, sew1, seb1, sew2, seb2, wgt);
  if (use_xn){
    k_mlp<<<2304, 256, 0, stream>>>(y2, ws1, wgt, 1, W1pk, w1gd, wcv, W2pk, mlp_b2, (float*)d_out);
  } else {
    k_combine<<<27648, 256, 0, stream>>>((const u16*)d_out, ws1, wgt, ws0);
    k_mlp<<<2304, 256, 0, stream>>>(ws0, ws0, wgt, 0, W1pk, w1gd, wcv, W2pk, mlp_b2, (float*)d_out);
  }
}

// Round 18
// 557.525 us; speedup vs baseline: 1.1099x; 1.0230x over previous
//
#include <hip/hip_runtime.h>
#include <hip/hip_bf16.h>

#define NWIN 576
#define SP 36864
#define ATT_SCALE 0.17677669529663687f

typedef unsigned short u16;
typedef unsigned int u32;
typedef __attribute__((ext_vector_type(8))) __bf16 bf16x8;
typedef __attribute__((ext_vector_type(4))) float f32x4;

__device__ __forceinline__ float b2f(u16 u){ return __uint_as_float(((u32)u)<<16); }
__device__ __forceinline__ u16 f2b(float f){ u32 u = __float_as_uint(f); return (u16)((u + 0x7FFFu + ((u>>16)&1u)) >> 16); }
__device__ __forceinline__ float fast_rcp(float d){ float r; asm("v_rcp_f32 %0, %1" : "=v"(r) : "v"(d)); return r; }
__device__ __forceinline__ u32 cvtpk(float lo, float hi){ u32 r; asm("v_cvt_pk_bf16_f32 %0, %1, %2" : "=v"(r) : "v"(lo), "v"(hi)); return r; }
// tanh-form GELU: x*sigmoid(1.59577(x+0.044715x^3)); |err vs erf-GELU| <~1e-3
__device__ __forceinline__ float gelu_f(float v){
  float u = v*(1.5957691216f + 0.0713548163f*v*v);
  return v * fast_rcp(1.0f + __expf(-u));
}
__device__ __forceinline__ f32x4 mfma16(bf16x8 a, bf16x8 b, f32x4 c){
  return __builtin_amdgcn_mfma_f32_16x16x32_bf16(a, b, c, 0, 0, 0);
}

// ---------------- transpose BCHW fp32 -> NHWC bf16 (4 h-rows per block) ----------------
__global__ __launch_bounds__(256) void k_transpose(const float* __restrict__ x, u16* __restrict__ xn){
  __shared__ float tile[32][33];
  int blk = blockIdx.x;
  int b = blk / 1728; int rem = blk % 1728;
  int hg = rem / 36; int rem2 = rem % 36;
  int wt = rem2 / 6, ct = rem2 % 6;
  int t = threadIdx.x;
  int lw = t & 31, g = t >> 5;
  for (int r4 = 0; r4 < 4; ++r4){
    int h = hg*4 + r4;
    for (int r = 0; r < 4; ++r){
      int cl = g + r*8;
      tile[cl][lw] = x[(((size_t)b*192 + ct*32 + cl)*192 + h)*192 + wt*32 + lw];
    }
    __syncthreads();
    for (int r = 0; r < 4; ++r){
      int wl = g + r*8;
      xn[(((size_t)b*192 + h)*192 + wt*32 + wl)*192 + ct*32 + lw] = f2b(tile[lw][wl]);
    }
    __syncthreads();
  }
}

// ---------------- all weight prep in one kernel ----------------
__global__ __launch_bounds__(256) void k_prep_all(
    const float* __restrict__ c1w, const float* __restrict__ c2w,
    const float* __restrict__ qkv_w, const float* __restrict__ rel_table,
    const float* __restrict__ mlp_w1, const float* __restrict__ mlp_w2,
    const float* __restrict__ n2g, const float* __restrict__ n2b, const float* __restrict__ mb1,
    const float* __restrict__ n1g, const float* __restrict__ n1b, const float* __restrict__ qkv_b,
    u16* __restrict__ Wpk1, u16* __restrict__ Wpk2, u16* __restrict__ Qkvpk,
    float* __restrict__ biasT, u16* __restrict__ W1pk, u16* __restrict__ W2pk,
    float* __restrict__ w1gd, float* __restrict__ wcv,
    float* __restrict__ qgd, float* __restrict__ qwc){
  int i = blockIdx.x*256 + threadIdx.x;
  if (i < 331776){
    int j = i & 7; int l = (i >> 3) & 63; int rem = i >> 9;
    int nt = rem % 12; int rem2 = rem / 12; int kc = rem2 % 6; int tap = rem2 / 6;
    int ci = kc*32 + ((l>>4)<<3) + j;
    int co = nt*16 + (l & 15);
    Wpk1[i] = f2b(c1w[(co*192 + ci)*9 + tap]);
    Wpk2[i] = f2b(c2w[(co*192 + ci)*9 + tap]);
    return;
  }
  i -= 331776;
  if (i < 110592){
    // qkv weights pre-scaled by norm1 gamma (LN1 fold)
    int j = i & 7; int l = (i >> 3) & 63; int rem = i >> 9;
    int kc = rem % 6; int nt = rem / 6;
    int row = nt*16 + (l & 15); int c = kc*32 + ((l>>4)<<3) + j;
    Qkvpk[i] = f2b(qkv_w[row*192 + c] * n1g[c]);
    return;
  }
  i -= 110592;
  if (i < 24576){
    // biasT[h][k][q]
    int q = i & 63; int k = (i>>6) & 63; int h = i >> 12;
    int di = (q>>3) - (k>>3) + 7; int dj = (q&7) - (k&7) + 7;
    biasT[i] = rel_table[(di*15 + dj)*6 + h];
    return;
  }
  i -= 24576;
  if (i < 147456){
    // W1 pre-scaled by norm2 gamma (LN fold)
    int j = i & 7; int l = (i >> 3) & 63; int rem = i >> 9;
    int kc = rem % 6; int nt = rem / 6;
    int ho = nt*16 + (l & 15); int ci = kc*32 + ((l>>4)<<3) + j;
    W1pk[i] = f2b(mlp_w1[ho*192 + ci] * n2g[ci]);
    return;
  }
  i -= 147456;
  if (i < 147456){
    int j = i & 7; int l = (i >> 3) & 63; int rem = i >> 9;
    int kc = rem % 24; int nt = rem / 24;
    int co = nt*16 + (l & 15); int ho = kc*32 + ((l>>4)<<3) + j;
    W2pk[i] = f2b(mlp_w2[co*768 + ho]);
    return;
  }
  i -= 147456;
  if (i < 768){
    // dot-vectors for mlp LN fold: w1gd = W1·g ; wcv = W1·b + mb1
    float sg = 0.f, sb = 0.f;
    const float* row = mlp_w1 + (size_t)i*192;
    for (int ci = 0; ci < 192; ++ci){ float w = row[ci]; sg += w*n2g[ci]; sb += w*n2b[ci]; }
    w1gd[i] = sg; wcv[i] = sb + mb1[i];
    return;
  }
  i -= 768;
  if (i < 576){
    // dot-vectors for qkv LN1 fold: qgd = Wq·g1 ; qwc = Wq·b1 + qkv_b
    float sg = 0.f, sb = 0.f;
    const float* row = qkv_w + (size_t)i*192;
    for (int c = 0; c < 192; ++c){ float w = row[c]; sg += w*n1g[c]; sb += w*n1b[c]; }
    qgd[i] = sg; qwc[i] = sb + qkv_b[i];
  }
}

// ---------------- fused shifted-window attention, LN1 folded into qkv weights ----------------
__global__ __launch_bounds__(768, 3) void k_attn(const float* __restrict__ x, const u16* __restrict__ xn, int use_xn,
    const u16* __restrict__ qkvpk, const float* __restrict__ qgd, const float* __restrict__ qwc,
    const float* __restrict__ biasT, u16* __restrict__ x1)
{
  __shared__ u16 xw[12800];            // [64][200]: RAW input -> (after qkv) O staging
  __shared__ u16 qs[6][64][40];
  __shared__ u16 ks[6][64][40];
  __shared__ u16 vt[6][32][72];
  __shared__ int ih[64], iw[64], rid[64];
  __shared__ float2 musig[64];         // (rsg, -rsg*mu)
  int blk = blockIdx.x, t = threadIdx.x;
  int b = blk / NWIN, wi = blk % NWIN, wy = wi / 24, wx = wi % 24;
  int wid = t >> 6, l = t & 63, l15 = l & 15, lg = l >> 4;
  if (t < 64){
    int i = t >> 3, j = t & 7;
    int gh = wy*8 + i, gw = wx*8 + j;
    int hf = gh + 4; if (hf >= 192) hf -= 192;
    int wf = gw + 4; if (wf >= 192) wf -= 192;
    ih[t] = hf; iw[t] = wf;
    int rh = (gh < 184) ? 0 : ((gh < 188) ? 1 : 2);
    int rw = (gw < 184) ? 0 : ((gw < 188) ? 1 : 2);
    rid[t] = rh*3 + rw;
  }
  __syncthreads();
  // ---- load RAW tokens ----
  if (use_xn){
    for (int idx = t; idx < 1536; idx += 768){
      int n = idx / 24, q = idx % 24;
      *(uint4*)&xw[n*200 + q*8] =
        *(const uint4*)(xn + ((size_t)((b*192 + ih[n])*192 + iw[n]))*192 + q*8);
    }
  } else {
    for (int idx = t; idx < 12288; idx += 768){
      int n = idx & 63, c = idx >> 6;
      xw[n*200 + c] = f2b(x[(((size_t)b*192 + c)*192 + ih[n])*192 + iw[n]]);
    }
  }
  __syncthreads();
  // ---- LN stats only (no transform): 64 toks x 8 parts x 24ch, 8-lane shfl reduce ----
  if (t < 512){
    int tok = t >> 3, part = t & 7;
    float s = 0.f, s2 = 0.f;
    #pragma unroll
    for (int i = 0; i < 3; ++i){
      uint4 v = *(const uint4*)&xw[tok*200 + part*8 + 64*i];
      u32* vp = (u32*)&v;
      #pragma unroll
      for (int q = 0; q < 4; ++q){
        float a = b2f((u16)(vp[q] & 0xffffu)), c2 = b2f((u16)(vp[q] >> 16));
        s += a + c2; s2 += a*a + c2*c2;
      }
    }
    #pragma unroll
    for (int d = 1; d < 8; d <<= 1){
      s  += __shfl_xor(s, d);
      s2 += __shfl_xor(s2, d);
    }
    if (part == 0){
      float m = s*(1.f/192.f); float v = s2*(1.f/192.f) - m*m;
      float rs = rsqrtf(v + 1e-5f);
      musig[tok] = make_float2(rs, -rs*m);
    }
  }
  __syncthreads();
  // ---- qkv GEMM on RAW x; LN applied in epilogue via per-token (rsg, -rsg*mu) ----
  {
    f32x4 acc[3][4];
    #pragma unroll
    for (int i3 = 0; i3 < 3; ++i3)
      #pragma unroll
      for (int mt = 0; mt < 4; ++mt) acc[i3][mt] = (f32x4){0.f,0.f,0.f,0.f};
    #pragma unroll
    for (int kc = 0; kc < 6; ++kc){
      bf16x8 a4[4];
      #pragma unroll
      for (int mt = 0; mt < 4; ++mt)
        a4[mt] = *(const bf16x8*)&xw[(mt*16 + l15)*200 + kc*32 + lg*8];
      #pragma unroll
      for (int i3 = 0; i3 < 3; ++i3){
        int ntg = wid*3 + i3;
        bf16x8 bf = *(const bf16x8*)(qkvpk + ((size_t)ntg*6 + kc)*512 + l*8);
        #pragma unroll
        for (int mt = 0; mt < 4; ++mt)
          acc[i3][mt] = mfma16(a4[mt], bf, acc[i3][mt]);
      }
    }
    float2 msr[4][4];
    #pragma unroll
    for (int mt = 0; mt < 4; ++mt)
      #pragma unroll
      for (int r = 0; r < 4; ++r)
        msr[mt][r] = musig[mt*16 + lg*4 + r];
    #pragma unroll
    for (int i3 = 0; i3 < 3; ++i3){
      int ntg = wid*3 + i3;
      int rowg = ntg*16 + l15;
      float gd = qgd[rowg];
      float wc = qwc[rowg];
      int m = ntg/12, hh = (ntg%12)>>1, hd0 = (ntg&1)*16;
      #pragma unroll
      for (int mt = 0; mt < 4; ++mt)
        #pragma unroll
        for (int r = 0; r < 4; ++r){
          int tok = mt*16 + lg*4 + r;
          float2 ms = msr[mt][r];
          float val = fmaf(ms.x, acc[i3][mt][r], fmaf(ms.y, gd, wc));
          if (m == 0){ qs[hh][tok][hd0 + l15] = f2b(val * ATT_SCALE); }
          else if (m == 1){ ks[hh][tok][hd0 + l15] = f2b(val); }
          else { vt[hh][hd0 + l15][tok] = f2b(val); }
        }
    }
  }
  __syncthreads();
  // ---- attention: wave = (head h, q-half mt0) ----
  int h = wid >> 1, mt0 = (wid & 1) * 2;
  // swapped QK^T: S^T frags, lane holds q = l15, k = nt*16 + lg*4 + r
  f32x4 st[2][4];
  {
    bf16x8 bq0 = *(const bf16x8*)&qs[h][(mt0  )*16 + l15][lg*8];
    bf16x8 bq1 = *(const bf16x8*)&qs[h][(mt0+1)*16 + l15][lg*8];
    #pragma unroll
    for (int nt = 0; nt < 4; ++nt){
      bf16x8 ak = *(const bf16x8*)&ks[h][nt*16 + l15][lg*8];
      st[0][nt] = mfma16(ak, bq0, (f32x4){0.f,0.f,0.f,0.f});
      st[1][nt] = mfma16(ak, bq1, (f32x4){0.f,0.f,0.f,0.f});
    }
  }
  // bias + mask + in-register softmax + pack to bf16 pairs
  u32 pk[2][4][2];
  #pragma unroll
  for (int m2 = 0; m2 < 2; ++m2){
    int qg = (mt0 + m2)*16 + l15;
    int rq = rid[qg];
    const float* bp = biasT + (size_t)h*4096 + qg;
    float mx = -1e30f;
    #pragma unroll
    for (int nt = 0; nt < 4; ++nt)
      #pragma unroll
      for (int r = 0; r < 4; ++r){
        int kg = nt*16 + lg*4 + r;
        float v = st[m2][nt][r] + bp[kg*64] + (rq != rid[kg] ? -100.f : 0.f);
        st[m2][nt][r] = v;
        mx = fmaxf(mx, v);
      }
    mx = fmaxf(mx, __shfl_xor(mx, 16));
    mx = fmaxf(mx, __shfl_xor(mx, 32));
    float ssum = 0.f;
    #pragma unroll
    for (int nt = 0; nt < 4; ++nt)
      #pragma unroll
      for (int r = 0; r < 4; ++r){
        float e = __expf(st[m2][nt][r] - mx);
        st[m2][nt][r] = e; ssum += e;
      }
    ssum += __shfl_xor(ssum, 16);
    ssum += __shfl_xor(ssum, 32);
    float inv = fast_rcp(ssum);
    #pragma unroll
    for (int nt = 0; nt < 4; ++nt){
      pk[m2][nt][0] = cvtpk(st[m2][nt][0]*inv, st[m2][nt][1]*inv);
      pk[m2][nt][1] = cvtpk(st[m2][nt][2]*inv, st[m2][nt][3]*inv);
    }
  }
  // PV: repack P via shfl into A-frags; B = V rows
  f32x4 o[2][2];
  #pragma unroll
  for (int m2 = 0; m2 < 2; ++m2)
    #pragma unroll
    for (int nd = 0; nd < 2; ++nd) o[m2][nd] = (f32x4){0.f,0.f,0.f,0.f};
  {
    int srcA = ((lg & 1) << 1)*16 + l15;
    bool hiSel = (lg & 2) != 0;
    #pragma unroll
    for (int kc = 0; kc < 2; ++kc){
      bf16x8 bv0 = *(const bf16x8*)&vt[h][l15][kc*32 + lg*8];
      bf16x8 bv1 = *(const bf16x8*)&vt[h][16 + l15][kc*32 + lg*8];
      #pragma unroll
      for (int m2 = 0; m2 < 2; ++m2){
        u32 q0 = __shfl((int)pk[m2][2*kc  ][0], srcA);
        u32 q1 = __shfl((int)pk[m2][2*kc+1][0], srcA);
        u32 q2 = __shfl((int)pk[m2][2*kc  ][1], srcA);
        u32 q3 = __shfl((int)pk[m2][2*kc+1][1], srcA);
        u32 q4 = __shfl((int)pk[m2][2*kc  ][0], srcA + 16);
        u32 q5 = __shfl((int)pk[m2][2*kc+1][0], srcA + 16);
        u32 q6 = __shfl((int)pk[m2][2*kc  ][1], srcA + 16);
        u32 q7 = __shfl((int)pk[m2][2*kc+1][1], srcA + 16);
        union { u32 u[4]; bf16x8 v; } ap;
        ap.u[0] = hiSel ? q1 : q0;
        ap.u[1] = hiSel ? q3 : q2;
        ap.u[2] = hiSel ? q5 : q4;
        ap.u[3] = hiSel ? q7 : q6;
        o[m2][0] = mfma16(ap.v, bv0, o[m2][0]);
        o[m2][1] = mfma16(ap.v, bv1, o[m2][1]);
      }
    }
  }
  // stage O into xw (input region dead after qkv barrier)
  #pragma unroll
  for (int m2 = 0; m2 < 2; ++m2)
    #pragma unroll
    for (int nd = 0; nd < 2; ++nd)
      #pragma unroll
      for (int r = 0; r < 4; ++r){
        int tok = (mt0 + m2)*16 + lg*4 + r;
        xw[tok*200 + h*32 + nd*16 + l15] = f2b(o[m2][nd][r]);
      }
  __syncthreads();
  // ---- residual add + store NHWC bf16 ----
  if (use_xn){
    for (int idx = t; idx < 1536; idx += 768){
      int n = idx / 24, q = idx % 24;
      size_t tokoff = (size_t)((b*192 + ih[n])*192 + iw[n]);
      uint4 xv = *(const uint4*)(xn + tokoff*192 + q*8);
      uint4 ov = *(const uint4*)&xw[n*200 + q*8];
      uint4 res;
      u32* xp = (u32*)&xv; u32* op = (u32*)&ov; u32* rp = (u32*)&res;
      #pragma unroll
      for (int w2 = 0; w2 < 4; ++w2){
        float a0 = b2f((u16)(xp[w2] & 0xffffu)) + b2f((u16)(op[w2] & 0xffffu));
        float a1 = b2f((u16)(xp[w2] >> 16))    + b2f((u16)(op[w2] >> 16));
        rp[w2] = (u32)f2b(a0) | ((u32)f2b(a1) << 16);
      }
      *(uint4*)(x1 + tokoff*192 + q*8) = res;
    }
  } else {
    for (int idx = t; idx < 12288; idx += 768){
      int n = idx & 63, c = idx >> 6;
      size_t tokoff = (size_t)((b*192 + ih[n])*192 + iw[n]);
      float sc = x[(((size_t)b*192 + c)*192 + ih[n])*192 + iw[n]];
      x1[tokoff*192 + c] = f2b(sc + b2f(xw[n*200 + c]));
    }
  }
}

// ---------------- depthwise 3x3 gate: x2 = x1 + dw(x1), 4h x 8w tiles, XCD-swizzled ----------------
__global__ __launch_bounds__(192) void k_gate(const u16* __restrict__ x1, const float* __restrict__ gw,
                                              const float* __restrict__ gb, u16* __restrict__ x2){
  int bid = blockIdx.x;
  int blk = (bid & 7) * 576 + (bid >> 3);    // 4608 = 8*576: each XCD gets contiguous h-range
  int wt = blk % 24; int rem = blk / 24;
  int hg = rem % 48; int b = rem / 48;
  int c = threadIdx.x;
  int w0 = wt*8, h0 = hg*4;
  float wr[9];
  #pragma unroll
  for (int p = 0; p < 9; ++p) wr[p] = gw[c*9 + p];
  float bias = gb[c];
  float in[6][10];
  #pragma unroll
  for (int dy = 0; dy < 6; ++dy){
    int hh = h0 + dy - 1;
    bool hok = (hh >= 0 && hh < 192);
    #pragma unroll
    for (int p = 0; p < 10; ++p){
      int ww = w0 + p - 1;
      bool ok = hok && (ww >= 0 && ww < 192);
      in[dy][p] = ok ? b2f(x1[(((size_t)b*192 + hh)*192 + ww)*192 + c]) : 0.f;
    }
  }
  #pragma unroll
  for (int i = 0; i < 4; ++i){
    size_t rowbase = ((size_t)b*192 + h0 + i)*192;
    #pragma unroll
    for (int j = 0; j < 8; ++j){
      float acc = bias;
      #pragma unroll
      for (int dy = 0; dy < 3; ++dy)
        #pragma unroll
        for (int dx = 0; dx < 3; ++dx)
          acc += in[i + dy][j + dx] * wr[dy*3 + dx];
      float v = in[i + 1][j + 1] + acc;
      x2[(rowbase + w0 + j)*192 + c] = f2b(v);
    }
  }
}

// ---------------- 3x3 full conv, NHWC, MFMA implicit GEMM, XCD-swizzled, optional fused pool ----------------
__global__ __launch_bounds__(256) void k_conv(const u16* __restrict__ src, const u16* __restrict__ wpk,
                                              const float* __restrict__ cb, u16* __restrict__ dst,
                                              int do_gelu, float* __restrict__ pp){
  __shared__ u16 tin[20592];   // [3][66][104] ci-half tile; reused as obuf[64][200]
  int bid = blockIdx.x;
  int blk = (bid & 7) * 288 + (bid >> 3);    // 2304 = 8*288: each XCD gets contiguous h-range (halo L2-hits)
  int b = blk / 576; int rem = blk % 576;
  int h = rem / 3; int w0 = (rem % 3) * 64;
  int t = threadIdx.x;
  int wid = t >> 6, l = t & 63;
  int l15 = l & 15, lg = l >> 4;
  f32x4 acc[4][3];
  #pragma unroll
  for (int mt = 0; mt < 4; ++mt)
    #pragma unroll
    for (int j = 0; j < 3; ++j) acc[mt][j] = (f32x4){0.f,0.f,0.f,0.f};
  for (int ch = 0; ch < 2; ++ch){
    __syncthreads();
    for (int idx = t; idx < 2376; idx += 256){
      int r = idx / 792; int r2 = idx % 792; int p = r2 / 12; int q = r2 % 12;
      int hh = h + r - 1, ww = w0 + p - 1;
      uint4 v = make_uint4(0u,0u,0u,0u);
      if (hh >= 0 && hh < 192 && ww >= 0 && ww < 192)
        v = *(const uint4*)(src + (((size_t)(b*192 + hh))*192 + ww)*192 + ch*96 + q*8);
      *(uint4*)&tin[(r*66 + p)*104 + q*8] = v;
    }
    __syncthreads();
    for (int dy = 0; dy < 3; ++dy){
      for (int kch = 0; kch < 3; ++kch){
        bf16x8 af[4][3];
        #pragma unroll
        for (int mt = 0; mt < 4; ++mt)
          #pragma unroll
          for (int dx = 0; dx < 3; ++dx)
            af[mt][dx] = *(const bf16x8*)&tin[(dy*66 + mt*16 + l15 + dx)*104 + kch*32 + lg*8];
        bf16x8 bw[3][3];
        int kc = ch*3 + kch;
        #pragma unroll
        for (int dx = 0; dx < 3; ++dx)
          #pragma unroll
          for (int j = 0; j < 3; ++j)
            bw[dx][j] = *(const bf16x8*)(wpk + ((((size_t)(dy*3+dx)*6 + kc)*12 + wid*3 + j)*64 + l)*8);
        __builtin_amdgcn_s_setprio(1);
        #pragma unroll
        for (int dx = 0; dx < 3; ++dx)
          #pragma unroll
          for (int j = 0; j < 3; ++j)
            #pragma unroll
            for (int mt = 0; mt < 4; ++mt)
              acc[mt][j] = mfma16(af[mt][dx], bw[dx][j], acc[mt][j]);
        __builtin_amdgcn_s_setprio(0);
      }
    }
  }
  __syncthreads();
  float bv[3];
  #pragma unroll
  for (int j = 0; j < 3; ++j) bv[j] = cb[wid*48 + j*16 + l15];
  #pragma unroll
  for (int mt = 0; mt < 4; ++mt)
    #pragma unroll
    for (int j = 0; j < 3; ++j)
      #pragma unroll
      for (int r = 0; r < 4; ++r){
        int pix = mt*16 + lg*4 + r;
        float v = acc[mt][j][r] + bv[j];
        if (do_gelu) v = gelu_f(v);
        tin[pix*200 + wid*48 + j*16 + l15] = f2b(v);
      }
  __syncthreads();
  for (int idx = t; idx < 1536; idx += 256){
    int pix = idx / 24, q = idx % 24;
    *(uint4*)(dst + (((size_t)(b*192 + h))*192 + w0 + pix)*192 + q*8) = *(const uint4*)&tin[pix*200 + q*8];
  }
  if (pp){
    // fused pool partial: sum over this block's 64 pixels per channel
    if (t < 192){
      float s = 0.f;
      #pragma unroll 8
      for (int pix = 0; pix < 64; ++pix) s += b2f(tin[pix*200 + t]);
      pp[(size_t)blk*192 + t] = s;
    }
  }
}

// ---------------- SE MLP (one block per batch; reduces 576 conv-block partials) ----------------
__global__ __launch_bounds__(256) void k_se(const float* __restrict__ pp, const float* __restrict__ w1,
    const float* __restrict__ bb1, const float* __restrict__ w2, const float* __restrict__ bb2,
    float* __restrict__ wgt){
  __shared__ float pb[192]; __shared__ float hq[12];
  int t = threadIdx.x;
  int b = blockIdx.x;
  if (t < 192){
    float s = 0.f;
    const float* base = pp + (size_t)b*576*192 + t;
    for (int ch = 0; ch < 576; ++ch) s += base[ch*192];
    pb[t] = s * (1.f/36864.f);
  }
  __syncthreads();
  if (t < 12){ float a = bb1[t]; for (int c = 0; c < 192; ++c) a += pb[c]*w1[t*192 + c]; hq[t] = fmaxf(a, 0.f); }
  __syncthreads();
  if (t < 192){ float a = bb2[t]; for (int m = 0; m < 12; ++m) a += hq[m]*w2[t*12 + m]; wgt[b*192 + t] = 1.f/(1.f + __expf(-a)); }
}

// ---------------- x3 = y2*wgt + x2 (fallback path only) ----------------
__global__ __launch_bounds__(256) void k_combine(const u16* __restrict__ y2, const u16* __restrict__ x2,
                                                 const float* __restrict__ wgt, u16* __restrict__ x3){
  size_t e = ((size_t)blockIdx.x*256 + threadIdx.x)*4;
  int c = (int)(e % 192);
  int b = (int)(e / ((size_t)SP*192));
  uint2 ya = *(const uint2*)(y2 + e);
  uint2 xa = *(const uint2*)(x2 + e);
  float4 wf = *(const float4*)(wgt + b*192 + c);
  float r0 = b2f((u16)(ya.x & 0xffffu))*wf.x + b2f((u16)(xa.x & 0xffffu));
  float r1 = b2f((u16)(ya.x >> 16))   *wf.y + b2f((u16)(xa.x >> 16));
  float r2 = b2f((u16)(ya.y & 0xffffu))*wf.z + b2f((u16)(xa.y & 0xffffu));
  float r3 = b2f((u16)(ya.y >> 16))   *wf.w + b2f((u16)(xa.y >> 16));
  uint2 o; o.x = (u32)f2b(r0) | ((u32)f2b(r1)<<16); o.y = (u32)f2b(r2) | ((u32)f2b(r3)<<16);
  *(uint2*)(x3 + e) = o;
}

// ---------------- fused [combine] + MLP with LN folded into W1 (MFMA, 64-tok, 4-phase hidQ) ----------------
__global__ __launch_bounds__(256, 2) void k_mlp(const u16* __restrict__ src0, const u16* __restrict__ src1,
    const float* __restrict__ wgt, int fused, const u16* __restrict__ W1pk,
    const float* __restrict__ w1gd, const float* __restrict__ wcv,
    const u16* __restrict__ W2pk, const float* __restrict__ mb2,
    float* __restrict__ out){
  __shared__ u16 lnS[64][200];         // raw combined x3 (NEVER overwritten)
  __shared__ u16 hidQ[64*192];         // quarter-hidden [tok][ho'], rows 384B, byte ^= ((tok&7)<<4)
  __shared__ float mu[64], rsg[64];
  int blk = blockIdx.x, t = threadIdx.x;
  int b = blk / 576; int rem = blk % 576;
  int h = rem / 3; int w0 = (rem % 3) * 64;
  size_t tokbase = ((size_t)b*192 + h)*192 + w0;
  int wid = t >> 6, l = t & 63, l15 = l & 15, lg = l >> 4;
  char* hb = (char*)hidQ;
  if (fused){
    for (int idx = t; idx < 1536; idx += 256){
      int tok = idx / 24, q = idx % 24;
      uint4 yv = *(const uint4*)(src0 + (tokbase + tok)*192 + q*8);
      uint4 xv = *(const uint4*)(src1 + (tokbase + tok)*192 + q*8);
      const float* wb = wgt + b*192 + q*8;
      uint4 res;
      u32* yp = (u32*)&yv; u32* xp = (u32*)&xv; u32* rp = (u32*)&res;
      #pragma unroll
      for (int w2 = 0; w2 < 4; ++w2){
        float r0 = b2f((u16)(yp[w2] & 0xffffu))*wb[2*w2]   + b2f((u16)(xp[w2] & 0xffffu));
        float r1 = b2f((u16)(yp[w2] >> 16))   *wb[2*w2+1] + b2f((u16)(xp[w2] >> 16));
        rp[w2] = cvtpk(r0, r1);
      }
      *(uint4*)&lnS[tok][q*8] = res;
    }
  } else {
    for (int idx = t; idx < 1536; idx += 256){
      int tok = idx / 24, q = idx % 24;
      *(uint4*)&lnS[tok][q*8] = *(const uint4*)(src0 + (tokbase + tok)*192 + q*8);
    }
  }
  __syncthreads();
  // stats: tok = t>>2, part = t&3; 48 ch per part (6 strided uint4), 4-lane shfl reduce
  { int tok = t >> 2, part = t & 3;
    float s = 0.f, s2 = 0.f;
    #pragma unroll
    for (int i = 0; i < 6; ++i){
      uint4 v = *(const uint4*)&lnS[tok][part*8 + 32*i];
      u32* vp = (u32*)&v;
      #pragma unroll
      for (int q = 0; q < 4; ++q){
        float a = b2f((u16)(vp[q] & 0xffffu)), c2 = b2f((u16)(vp[q] >> 16));
        s += a + c2; s2 += a*a + c2*c2;
      }
    }
    #pragma unroll
    for (int d = 1; d < 4; d <<= 1){
      s  += __shfl_xor(s, d);
      s2 += __shfl_xor(s2, d);
    }
    if (part == 0){
      float m = s*(1.f/192.f); float v = s2*(1.f/192.f) - m*m;
      mu[tok] = m; rsg[tok] = rsqrtf(v + 1e-5f);
    } }
  __syncthreads();
  // per-lane LN scalars (tok = tt*16 + l15 is lane-constant in swapped GEMM1)
  float rsgL[4], rmuL[4];
  #pragma unroll
  for (int tt = 0; tt < 4; ++tt){
    rsgL[tt] = rsg[tt*16 + l15];
    rmuL[tt] = rsgL[tt]*mu[tt*16 + l15];
  }
  int nb = wid*3;
  // four phases: GEMM1 quarter (ho' 192-wide) -> GEMM2 partial (kc 6); acc2 carried
  f32x4 acc2[4][3];
  #pragma unroll
  for (int mt = 0; mt < 4; ++mt)
    #pragma unroll
    for (int j = 0; j < 3; ++j) acc2[mt][j] = (f32x4){0.f,0.f,0.f,0.f};
  #pragma unroll
  for (int ph = 0; ph < 4; ++ph){
    // hoist W1 frags + dot-vectors for this phase's 3 ho-tiles (batch-issued L2 loads)
    bf16x8 aw[3][6];
    float4 gd[3], wc4[3];
    #pragma unroll
    for (int i = 0; i < 3; ++i){
      int hot = ph*12 + wid*3 + i;
      #pragma unroll
      for (int kc = 0; kc < 6; ++kc)
        aw[i][kc] = *(const bf16x8*)(W1pk + ((size_t)(hot*6 + kc)*64 + l)*8);
      gd[i]  = *(const float4*)(w1gd + hot*16 + lg*4);
      wc4[i] = *(const float4*)(wcv + hot*16 + lg*4);
    }
    // GEMM1: D[ho][tok] = W1g x x3^T; LN applied in epilogue
    #pragma unroll
    for (int tt = 0; tt < 4; ++tt){
      bf16x8 bT[6];
      #pragma unroll
      for (int kc = 0; kc < 6; ++kc)
        bT[kc] = *(const bf16x8*)&lnS[tt*16 + l15][kc*32 + lg*8];
      #pragma unroll
      for (int i = 0; i < 3; ++i){
        f32x4 acc = (f32x4){0.f,0.f,0.f,0.f};
        __builtin_amdgcn_s_setprio(1);
        #pragma unroll
        for (int kc = 0; kc < 6; ++kc)
          acc = mfma16(aw[i][kc], bT[kc], acc);
        __builtin_amdgcn_s_setprio(0);
        float h0 = fmaf(rsgL[tt], acc[0], fmaf(-rmuL[tt], gd[i].x, wc4[i].x));
        float h1 = fmaf(rsgL[tt], acc[1], fmaf(-rmuL[tt], gd[i].y, wc4[i].y));
        float h2 = fmaf(rsgL[tt], acc[2], fmaf(-rmuL[tt], gd[i].z, wc4[i].z));
        float h3 = fmaf(rsgL[tt], acc[3], fmaf(-rmuL[tt], gd[i].w, wc4[i].w));
        u32 p0 = cvtpk(gelu_f(h0), gelu_f(h1));
        u32 p1 = cvtpk(gelu_f(h2), gelu_f(h3));
        int tok = tt*16 + l15;
        int hoL = (wid*3 + i)*16 + lg*4;   // local ho' in [0,192)
        int byt = (tok*384 + hoL*2) ^ ((l15 & 7) << 4);
        *(uint2*)(hb + byt) = make_uint2(p0, p1);
      }
    }
    __syncthreads();
    // GEMM2 partial: local kc in [0,6), global k-chunk = ph*6 + kc
    #pragma unroll 2
    for (int kc = 0; kc < 6; ++kc){
      bf16x8 a[4];
      #pragma unroll
      for (int mt = 0; mt < 4; ++mt){
        int by = ((mt*16 + l15)*384 + (kc*32 + lg*8)*2) ^ ((l15 & 7) << 4);
        a[mt] = *(const bf16x8*)(hb + by);
      }
      bf16x8 bw3[3];
      #pragma unroll
      for (int j = 0; j < 3; ++j)
        bw3[j] = *(const bf16x8*)(W2pk + (((size_t)(nb + j)*24 + ph*6 + kc)*64 + l)*8);
      __builtin_amdgcn_s_setprio(1);
      #pragma unroll
      for (int j = 0; j < 3; ++j)
        #pragma unroll
        for (int mt = 0; mt < 4; ++mt)
          acc2[mt][j] = mfma16(a[mt], bw3[j], acc2[mt][j]);
      __builtin_amdgcn_s_setprio(0);
    }
    __syncthreads();
  }
  // epilogue: bias + residual (lnS intact), float4 stores to BCHW
  #pragma unroll
  for (int j = 0; j < 3; ++j){
    int co = (nb + j)*16 + l15;
    float bj = mb2[co];
    #pragma unroll
    for (int mt = 0; mt < 4; ++mt){
      int tok0 = mt*16 + lg*4;
      float4 ov;
      #pragma unroll
      for (int r = 0; r < 4; ++r)
        ((float*)&ov)[r] = b2f(lnS[tok0 + r][co]) + acc2[mt][j][r] + bj;
      *(float4*)(out + (((size_t)b*192 + co)*192 + h)*192 + w0 + tok0) = ov;
    }
  }
}

extern "C" void kernel_launch(void* const* d_in, const int* in_sizes, int n_in,
                              void* d_out, int out_size, void* d_ws, size_t ws_size,
                              hipStream_t stream){
  const float* x      = (const float*)d_in[0];
  const float* n1g    = (const float*)d_in[1];
  const float* n1b    = (const float*)d_in[2];
  const float* qkv_w  = (const float*)d_in[3];
  const float* qkv_b  = (const float*)d_in[4];
  const float* rel_t  = (const float*)d_in[5];
  const float* n2g    = (const float*)d_in[6];
  const float* n2b    = (const float*)d_in[7];
  const float* mlp_w1 = (const float*)d_in[8];
  const float* mlp_b1 = (const float*)d_in[9];
  const float* mlp_w2 = (const float*)d_in[10];
  const float* mlp_b2 = (const float*)d_in[11];
  const float* c1w    = (const float*)d_in[12];
  const float* c1b    = (const float*)d_in[13];
  const float* c2w    = (const float*)d_in[14];
  const float* c2b    = (const float*)d_in[15];
  const float* sew1   = (const float*)d_in[16];
  const float* seb1   = (const float*)d_in[17];
  const float* sew2   = (const float*)d_in[18];
  const float* seb2   = (const float*)d_in[19];
  const float* gw     = (const float*)d_in[20];
  const float* gb     = (const float*)d_in[21];

  const size_t E  = (size_t)4*192*192*192;
  const size_t EB = E*2;
  const size_t SMALL = 663552*2 + 221184 + 98304 + 294912*2 + 4*576*192*4 + 768*4*3 + 576*4*2 + 65536;
  char* ws = (char*)d_ws;
  u16* ws0 = (u16*)(ws);
  u16* ws1 = (u16*)(ws + EB);
  size_t off = 2*EB;
  int use_xn = (ws_size >= 3*EB + SMALL) ? 1 : 0;
  u16* xn = nullptr;
  if (use_xn){ xn = (u16*)(ws + off); off += EB; }
  u16* Wpk1  = (u16*)(ws + off); off += 663552;
  u16* Wpk2  = (u16*)(ws + off); off += 663552;
  u16* Qkvpk = (u16*)(ws + off); off += 221184;
  float* biasT = (float*)(ws + off); off += 98304;
  u16* W1pk = (u16*)(ws + off); off += 294912;
  u16* W2pk = (u16*)(ws + off); off += 294912;
  float* w1gd = (float*)(ws + off); off += 768*4;
  float* wcv  = (float*)(ws + off); off += 768*4;
  float* qgd  = (float*)(ws + off); off += 576*4;
  float* qwc  = (float*)(ws + off); off += 576*4;
  float* pp  = (float*)(ws + off); off += (size_t)4*576*192*4;
  float* wgt = (float*)(ws + off); off += 768*4;

  if (use_xn) k_transpose<<<6912, 256, 0, stream>>>(x, xn);
  k_prep_all<<<2982, 256, 0, stream>>>(c1w, c2w, qkv_w, rel_t, mlp_w1, mlp_w2,
                                       n2g, n2b, mlp_b1, n1g, n1b, qkv_b,
                                       Wpk1, Wpk2, Qkvpk, biasT, W1pk, W2pk, w1gd, wcv, qgd, qwc);

  k_attn<<<2304, 768, 0, stream>>>(x, xn, use_xn, Qkvpk, qgd, qwc, biasT, ws0);
  k_gate<<<4608, 192, 0, stream>>>(ws0, gw, gb, ws1);
  k_conv<<<2304, 256, 0, stream>>>(ws1, Wpk1, c1b, ws0, 1, nullptr);
  u16* y2 = use_xn ? xn : (u16*)d_out;
  k_conv<<<2304, 256, 0, stream>>>(ws0, Wpk2, c2b, y2, 0, pp);
  k_se<<<4, 256, 0, stream>>>(pp, sew1, seb1, sew2, seb2, wgt);
  if (use_xn){
    k_mlp<<<2304, 256, 0, stream>>>(y2, ws1, wgt, 1, W1pk, w1gd, wcv, W2pk, mlp_b2, (float*)d_out);
  } else {
    k_combine<<<27648, 256, 0, stream>>>((const u16*)d_out, ws1, wgt, ws0);
    k_mlp<<<2304, 256, 0, stream>>>(ws0, ws0, wgt, 0, W1pk, w1gd, wcv, W2pk, mlp_b2, (float*)d_out);
  }
}